// Round 1
// baseline (302.315 us; speedup 1.0000x reference)
//
#include <hip/hip_runtime.h>
#include <hip/hip_bf16.h>
#include <math.h>

#define N_NODES 50000
#define F_IN 128
#define HID 64
#define NCLS 40
#define K_STACKS 2
#define SCAN_TILE 1024
#define NBLK_CNT 256  // radix blocks; 256 buckets of 256 node-ids (N=50000 -> 196 used)

typedef __attribute__((ext_vector_type(8))) short short8;
typedef __attribute__((ext_vector_type(4))) float floatx4;
typedef __attribute__((ext_vector_type(2))) float floatx2;

__device__ __forceinline__ unsigned int f32_to_bf16_bits(float f) {
    unsigned int u = __float_as_uint(f);
    return (u + 0x7fffu + ((u >> 16) & 1u)) >> 16;  // RNE
}
__device__ __forceinline__ unsigned int pack_bf16x2(float a, float b) {
    return f32_to_bf16_bits(a) | (f32_to_bf16_bits(b) << 16);
}
__device__ __forceinline__ unsigned char f32_to_fp8(float v) {
    int pk = __builtin_amdgcn_cvt_pk_fp8_f32(v, v, 0, false);  // OCP e4m3 on gfx950
    return (unsigned char)(pk & 0xff);
}

// ---------------- CSR build via radix bucketing (dst>>8) ----------------
// NOTE: packing src into 16 bits requires N <= 65536 (here N=50000).

__global__ __launch_bounds__(256) void count_kernel(const int* __restrict__ dst,
                                                    int* __restrict__ counts,
                                                    int* __restrict__ tileSums, int E) {
    __shared__ int hist[256];
    __shared__ int ts[64];
    int blk = blockIdx.x, t = threadIdx.x;
    hist[t] = 0;
    if (t < 64) ts[t] = 0;
    __syncthreads();
    int chunk = (E + NBLK_CNT - 1) / NBLK_CNT;
    int s = blk * chunk, e = min(E, s + chunk);
    for (int i = s + t; i < e; i += 256) atomicAdd(&hist[dst[i] >> 8], 1);
    __syncthreads();
    counts[t * NBLK_CNT + blk] = hist[t];  // bucket-major
    atomicAdd(&ts[t >> 2], hist[t]);
    __syncthreads();
    if (t < 64) atomicAdd(&tileSums[t], ts[t]);
}

__global__ __launch_bounds__(256) void scan_phase3_excl(const int* __restrict__ in,
                                                        const int* __restrict__ tileSums,
                                                        int* __restrict__ out, int n) {
    __shared__ int lds[256];
    __shared__ int tsum[64];
    int b = blockIdx.x, t = threadIdx.x;
    if (t < 64) tsum[t] = tileSums[t];
    int base = b * SCAN_TILE + t * 4;
    int e[4];
    int s = 0;
#pragma unroll
    for (int i = 0; i < 4; ++i) {
        e[i] = (base + i < n) ? in[base + i] : 0;
        s += e[i];
    }
    lds[t] = s;
    __syncthreads();
    int v = s;
    for (int off = 1; off < 256; off <<= 1) {
        int add = (t >= off) ? lds[t - off] : 0;
        __syncthreads();
        v += add;
        lds[t] = v;
        __syncthreads();
    }
    int toff = 0;
    for (int i = 0; i < b; ++i) toff += tsum[i];
    int run = (t == 0 ? 0 : lds[t - 1]) + toff;
#pragma unroll
    for (int i = 0; i < 4; ++i) {
        if (base + i < n) {
            out[base + i] = run;
            run += e[i];
        }
    }
}

__global__ __launch_bounds__(256) void bucket_scatter_kernel(const int* __restrict__ src,
                                                             const int* __restrict__ dst,
                                                             const int* __restrict__ scanned,
                                                             unsigned int* __restrict__ pairs,
                                                             int E) {
    __shared__ int cur[256];
    int blk = blockIdx.x, t = threadIdx.x;
    cur[t] = scanned[t * NBLK_CNT + blk];
    __syncthreads();
    int chunk = (E + NBLK_CNT - 1) / NBLK_CNT;
    int s0 = blk * chunk, e0 = min(E, s0 + chunk);
    for (int i = s0 + t; i < e0; i += 256) {
        int d = dst[i];
        int pos = atomicAdd(&cur[d >> 8], 1);
        pairs[pos] = (unsigned int)src[i] | ((unsigned int)(d & 255) << 16);
    }
}

__global__ __launch_bounds__(256) void csr_build_kernel(const unsigned int* __restrict__ pairs,
                                                        const int* __restrict__ scanned,
                                                        int* __restrict__ row_ptr,
                                                        float* __restrict__ dinv,
                                                        int* __restrict__ col, int N, int E) {
    __shared__ int degl[256], lds[256], curl[256], sb[2];
    int b = blockIdx.x, t = threadIdx.x;
    if (t == 0) {
        sb[0] = scanned[b * NBLK_CNT];
        sb[1] = (b + 1 < 256) ? scanned[(b + 1) * NBLK_CNT] : E;
    }
    degl[t] = 0;
    __syncthreads();
    int bstart = sb[0], bend = sb[1];
    for (int e = bstart + t; e < bend; e += 256) {
        atomicAdd(&degl[(pairs[e] >> 16) & 255], 1);
    }
    __syncthreads();
    int d = degl[t];
    lds[t] = d;
    __syncthreads();
    int v = d;
    for (int off = 1; off < 256; off <<= 1) {
        int add = (t >= off) ? lds[t - off] : 0;
        __syncthreads();
        v += add;
        lds[t] = v;
        __syncthreads();
    }
    int excl = v - d;
    int node = b * 256 + t;
    if (node <= N) row_ptr[node] = bstart + excl;
    if (node < N) dinv[node] = (d > 0) ? (1.0f / sqrtf((float)d)) : 0.0f;
    curl[t] = excl;
    __syncthreads();
    for (int e = bstart + t; e < bend; e += 256) {
        unsigned int p = pairs[e];
        int ln = (p >> 16) & 255;
        int pos = atomicAdd(&curl[ln], 1);
        col[bstart + pos] = (int)(p & 0xffffu);
    }
}

// ---------------- fused weight pre-transpose: [k][C][F] fp32 -> [k][F][CP] bf16 ----------
__device__ __forceinline__ void wt_one(const float* __restrict__ in,
                                       unsigned short* __restrict__ out, int li, int C, int F,
                                       int CP) {
    int k = li / (F * CP);
    int r = li - k * F * CP;
    int f = r / CP;
    int c = r - f * CP;
    out[li] = (c < C) ? (unsigned short)f32_to_bf16_bits(in[((size_t)k * C + c) * F + f]) : 0;
}

__global__ void wt_all_kernel(const float* v1, const float* w1i, const float* w1,
                              const float* v2, const float* w2i, const float* w2,
                              unsigned short* v1t, unsigned short* w1it, unsigned short* w1t,
                              unsigned short* v2t, unsigned short* w2it, unsigned short* w2t) {
    int i = blockIdx.x * blockDim.x + threadIdx.x;
    if (i < 16384) wt_one(v1, v1t, i, 128, 64, 128);
    else if (i < 32768) wt_one(w1i, w1it, i - 16384, 128, 64, 128);
    else if (i < 40960) wt_one(w1, w1t, i - 32768, 64, 64, 64);
    else if (i < 46080) wt_one(v2, v2t, i - 40960, 64, 40, 64);
    else if (i < 51200) wt_one(w2i, w2it, i - 46080, 64, 40, 64);
    else if (i < 56320) wt_one(w2, w2t, i - 51200, 40, 40, 64);
}

// ---------------- staging helpers ----------------
template <int CINP>
__device__ __forceinline__ void stage_A(const void* A, unsigned short* At, size_t abase,
                                        int n0, int t, int N, int CREAL, int a_bf16) {
    constexpr int CP8 = CINP / 8;
    constexpr int MS = CP8 - 1;
    constexpr int SH = (CP8 == 16) ? 4 : 3;
    for (int i = t; i < 64 * CP8; i += 256) {
        int n = i >> SH;
        int c = i & MS;
        uint4 w = make_uint4(0u, 0u, 0u, 0u);
        int gn = n0 + n;
        if (gn < N && c * 8 < CREAL) {
            if (a_bf16) {
                w = *(const uint4*)((const unsigned short*)A + abase + (size_t)gn * CREAL + c * 8);
            } else {
                const float* srcp = (const float*)A + abase + (size_t)gn * CREAL + c * 8;
                float4 f0 = *(const float4*)(srcp);
                float4 f1 = *(const float4*)(srcp + 4);
                w.x = pack_bf16x2(f0.x, f0.y);
                w.y = pack_bf16x2(f0.z, f0.w);
                w.z = pack_bf16x2(f1.x, f1.y);
                w.w = pack_bf16x2(f1.z, f1.w);
            }
        }
        *(uint4*)(At + n * CINP + ((c ^ (n & MS)) << 3)) = w;
    }
}

template <int CINP>
__device__ __forceinline__ void stage_B(const unsigned short* Bk, unsigned short* Bs, int t,
                                        int COUT) {
    constexpr int CP8 = CINP / 8;
    constexpr int MS = CP8 - 1;
    constexpr int SH = (CP8 == 16) ? 4 : 3;
    for (int i = t; i < COUT * CP8; i += 256) {
        int f = i >> SH;
        int c = i & MS;
        uint4 w = *(const uint4*)(Bk + f * CINP + c * 8);
        *(uint4*)(Bs + f * CINP + ((c ^ (f & MS)) << 3)) = w;
    }
}

// ---------------- layer-1 entry GEMM: x (f32) -> root1 (bf16 std) + table0 (fp8, dinv-scaled)
// k-loop inside the block: stage A once, iterate both stacks' B tiles.
__global__ __launch_bounds__(256) void gemm12_kernel(
    const float* __restrict__ A, const unsigned short* __restrict__ Bt1,
    const unsigned short* __restrict__ Bt2, unsigned short* __restrict__ out1,
    unsigned char* __restrict__ out2, const float* __restrict__ scale, int N) {
    constexpr int CINP = 128;
    constexpr int MS = 15;
    __shared__ __align__(16) unsigned short At[64 * CINP];
    __shared__ __align__(16) unsigned short Bs1[64 * CINP];
    __shared__ __align__(16) unsigned short Bs2[64 * CINP];
    const int n0 = blockIdx.x * 64;
    const int t = threadIdx.x;
    stage_A<CINP>(A, At, 0, n0, t, N, CINP, 0);
    const int lane = t & 63;
    const int wv = t >> 6;
    const int quad = lane >> 4;
    const int li = lane & 15;
    const int m0 = wv * 16;
    const int am = (m0 + li) & MS;
#pragma unroll 1
    for (int k = 0; k < 2; ++k) {
        stage_B<CINP>(Bt1 + (size_t)k * 64 * CINP, Bs1, t, 64);
        stage_B<CINP>(Bt2 + (size_t)k * 64 * CINP, Bs2, t, 64);
        __syncthreads();
        floatx4 acc1[4] = {{0.f, 0.f, 0.f, 0.f}, {0.f, 0.f, 0.f, 0.f},
                           {0.f, 0.f, 0.f, 0.f}, {0.f, 0.f, 0.f, 0.f}};
        floatx4 acc2[4] = {{0.f, 0.f, 0.f, 0.f}, {0.f, 0.f, 0.f, 0.f},
                           {0.f, 0.f, 0.f, 0.f}, {0.f, 0.f, 0.f, 0.f}};
#pragma unroll
        for (int kc = 0; kc < 4; ++kc) {
            int cc = kc * 4 + quad;
            short8 a = *(const short8*)(At + (m0 + li) * CINP + ((cc ^ am) << 3));
#pragma unroll
            for (int nt = 0; nt < 4; ++nt) {
                int f = nt * 16 + li;
                int bo = f * CINP + ((cc ^ (f & MS)) << 3);
                short8 b1 = *(const short8*)(Bs1 + bo);
                short8 b2 = *(const short8*)(Bs2 + bo);
                acc1[nt] = __builtin_amdgcn_mfma_f32_16x16x32_bf16(a, b1, acc1[nt], 0, 0, 0);
                acc2[nt] = __builtin_amdgcn_mfma_f32_16x16x32_bf16(a, b2, acc2[nt], 0, 0, 0);
            }
        }
        float sc[4];
#pragma unroll
        for (int r = 0; r < 4; ++r) {
            int node = n0 + m0 + quad * 4 + r;
            sc[r] = (node < N) ? scale[node] : 1.f;
        }
#pragma unroll
        for (int nt = 0; nt < 4; ++nt) {
            int f = nt * 16 + li;
#pragma unroll
            for (int r = 0; r < 4; ++r) {
                int node = n0 + m0 + quad * 4 + r;
                if (node < N) {
                    out1[((size_t)k * N + node) * 64 + f] =
                        (unsigned short)f32_to_bf16_bits(acc1[nt][r]);
                    out2[(size_t)node * 128 + (size_t)k * 64 + f] = f32_to_fp8(acc2[nt][r] * sc[r]);
                }
            }
        }
        __syncthreads();
    }
}

// ---------------- fused aggregation + GEMM ----------------
// Phase 1: per-wave gather/aggregate (2 nodes per pass, 8 passes -> 16 rows/wave) with the
// verified agg inner loop; epilogue (dinv scale + root + bias [+relu][+mean-over-k]) writes
// the result straight into the swizzled LDS A-tile.
// Phase 2: verified MFMA loop (CINP=64) against pre-staged B tiles; outputs the next fp8
// gather table (dinv[src]-prescaled) and, for FMODE==1, the layer-2 root (bf16).
// FMODE 0: per-k A, relu       (layer 1, t=1)    COUT=64, 1 B/k
// FMODE 1: mean-over-k A, relu (layer 2 entry)   COUT=40, 2 B/k  (root out + table out)
// FMODE 2: per-k A, no relu    (layer 2, t=1)    COUT=40, 1 B/k
template <int F, int COUT, int FMODE>
__global__ __launch_bounds__(256) void agg_gemm_kernel(
    const unsigned char* __restrict__ h8, const int* __restrict__ row_ptr,
    const int* __restrict__ col, const float* __restrict__ dinv,
    const unsigned short* __restrict__ rootb, const float* __restrict__ bias,
    const unsigned short* __restrict__ Bt1, const unsigned short* __restrict__ Bt2,
    unsigned short* __restrict__ rootOut, unsigned char* __restrict__ tblOut, int N) {
    constexpr int NA = (FMODE == 1) ? 1 : 2;
    constexpr int NB = (FMODE == 1) ? 4 : 2;
    constexpr int BT = COUT * 64;
    constexpr int NT = (COUT + 15) / 16;
    constexpr int FH = F / 8;
    constexpr int ROWB = 2 * F;
    __shared__ __align__(16) unsigned short At[NA * 64 * 64];
    __shared__ __align__(16) unsigned short Bs[NB * BT];
    __shared__ int rp[65];
    __shared__ float dvl[64];

    const int n0 = blockIdx.x * 64;
    const int t = threadIdx.x;

    stage_B<64>(Bt1, Bs, t, COUT);
    stage_B<64>(Bt1 + (size_t)COUT * 64, Bs + BT, t, COUT);
    if constexpr (FMODE == 1) {
        stage_B<64>(Bt2, Bs + 2 * BT, t, COUT);
        stage_B<64>(Bt2 + (size_t)COUT * 64, Bs + 3 * BT, t, COUT);
    }
    if (t < 65) rp[t] = row_ptr[min(n0 + t, N)];
    if (t < 64) dvl[t] = (n0 + t < N) ? dinv[n0 + t] : 0.f;
    __syncthreads();

    const int lane = t & 63;
    const int wv = t >> 6;
    const int half = lane >> 5;
    const int l32 = lane & 31;
    const int sub = l32 >> 4;
    const int fq = l32 & 15;
    const int kk = fq >> 3;
    const int fqq = fq & 7;
    const int fqc = (fqq < FH) ? fqq : (FH - 1);
    const int foff = kk * F + fqc * 8;

    // ---- phase 1: aggregate 16 rows per wave into LDS A ----
#pragma unroll 1
    for (int p = 0; p < 8; ++p) {
        const int nl = wv * 16 + p * 2 + half;
        const int node = n0 + nl;
        const bool valid = node < N;
        const int e0 = rp[nl];
        const int deg = rp[nl + 1] - e0;
        const float dv = dvl[nl];
        float acc[8] = {};
        for (int w0 = 0; w0 < deg; w0 += 32) {
            int mye = w0 + l32;
            int c = (mye < deg) ? col[e0 + mye] : 0;
            int nch = min(deg - w0, 32);
            for (int base = 0; base < nch; base += 16) {
                uint2 v[8];
                float wj[8];
#pragma unroll
                for (int u = 0; u < 8; ++u) {
                    int j = base + u * 2 + sub;
                    int cj = __shfl(c, (half << 5) | (j & 31));
                    bool ok = (j < nch);
                    wj[u] = ok ? 1.f : 0.f;
                    int cs = ok ? cj : 0;
                    v[u] = *(const uint2*)(h8 + (size_t)cs * ROWB + foff);
                }
#pragma unroll
                for (int u = 0; u < 8; ++u) {
                    floatx2 f0 = __builtin_amdgcn_cvt_pk_f32_fp8(v[u].x, false);
                    floatx2 f1 = __builtin_amdgcn_cvt_pk_f32_fp8(v[u].x, true);
                    floatx2 f2 = __builtin_amdgcn_cvt_pk_f32_fp8(v[u].y, false);
                    floatx2 f3 = __builtin_amdgcn_cvt_pk_f32_fp8(v[u].y, true);
                    acc[0] += wj[u] * f0.x;
                    acc[1] += wj[u] * f0.y;
                    acc[2] += wj[u] * f1.x;
                    acc[3] += wj[u] * f1.y;
                    acc[4] += wj[u] * f2.x;
                    acc[5] += wj[u] * f2.y;
                    acc[6] += wj[u] * f3.x;
                    acc[7] += wj[u] * f3.y;
                }
            }
        }
#pragma unroll
        for (int i = 0; i < 8; ++i) acc[i] += __shfl_xor(acc[i], 16);

        size_t oc = ((size_t)kk * N + (valid ? node : 0)) * F + fqc * 8;
        uint4 rv = *(const uint4*)(rootb + oc);
        const float* bp = bias + kk * F + fqc * 8;
        float4 b0 = *(const float4*)(bp);
        float4 b1_ = *(const float4*)(bp + 4);
        const unsigned int ru[4] = {rv.x, rv.y, rv.z, rv.w};
        float res[8];
#pragma unroll
        for (int q = 0; q < 4; ++q) {
            float rlo = __uint_as_float(ru[q] << 16);
            float rhi = __uint_as_float(ru[q] & 0xffff0000u);
            float blo = (q < 2) ? ((q == 0) ? b0.x : b0.z) : ((q == 2) ? b1_.x : b1_.z);
            float bhi = (q < 2) ? ((q == 0) ? b0.y : b0.w) : ((q == 2) ? b1_.y : b1_.w);
            res[2 * q] = acc[2 * q] * dv + rlo + blo;
            res[2 * q + 1] = acc[2 * q + 1] * dv + rhi + bhi;
        }
        if constexpr (FMODE != 2) {
#pragma unroll
            for (int i = 0; i < 8; ++i) res[i] = fmaxf(res[i], 0.f);
        }
        if constexpr (FMODE == 1) {
            float mres[8];
#pragma unroll
            for (int i = 0; i < 8; ++i) mres[i] = 0.5f * (res[i] + __shfl_xor(res[i], 8));
            if (sub == 0 && kk == 0) {
                uint4 w;
                w.x = pack_bf16x2(mres[0], mres[1]);
                w.y = pack_bf16x2(mres[2], mres[3]);
                w.z = pack_bf16x2(mres[4], mres[5]);
                w.w = pack_bf16x2(mres[6], mres[7]);
                *(uint4*)(At + nl * 64 + ((fqq ^ (nl & 7)) << 3)) = w;
            }
        } else {
            if (sub == 0) {
                uint4 w = make_uint4(0u, 0u, 0u, 0u);
                if (fqq < FH) {
                    w.x = pack_bf16x2(res[0], res[1]);
                    w.y = pack_bf16x2(res[2], res[3]);
                    w.z = pack_bf16x2(res[4], res[5]);
                    w.w = pack_bf16x2(res[6], res[7]);
                }
                *(uint4*)(At + kk * 4096 + nl * 64 + ((fqq ^ (nl & 7)) << 3)) = w;
            }
        }
    }
    __syncthreads();

    // ---- phase 2: MFMA over the LDS tile(s) ----
    const int quad = lane >> 4;
    const int li = lane & 15;
    const int m0 = wv * 16;
    const int am = (m0 + li) & 7;

    if constexpr (FMODE == 1) {
        floatx4 aR[2][NT] = {};
        floatx4 aT[2][NT] = {};
#pragma unroll
        for (int kc = 0; kc < 2; ++kc) {
            int cc = kc * 4 + quad;
            short8 a = *(const short8*)(At + (m0 + li) * 64 + ((cc ^ am) << 3));
#pragma unroll
            for (int nt = 0; nt < NT; ++nt) {
                int f = nt * 16 + li;
                int fc = (COUT & 15) ? ((f < COUT) ? f : (COUT - 1)) : f;
                int bo = fc * 64 + ((cc ^ (fc & 7)) << 3);
#pragma unroll
                for (int k = 0; k < 2; ++k) {
                    short8 bR = *(const short8*)(Bs + k * BT + bo);
                    short8 bT = *(const short8*)(Bs + (2 + k) * BT + bo);
                    aR[k][nt] = __builtin_amdgcn_mfma_f32_16x16x32_bf16(a, bR, aR[k][nt], 0, 0, 0);
                    aT[k][nt] = __builtin_amdgcn_mfma_f32_16x16x32_bf16(a, bT, aT[k][nt], 0, 0, 0);
                }
            }
        }
#pragma unroll
        for (int k = 0; k < 2; ++k) {
#pragma unroll
            for (int nt = 0; nt < NT; ++nt) {
                int f = nt * 16 + li;
                if (f >= COUT) continue;
#pragma unroll
                for (int r = 0; r < 4; ++r) {
                    int nl2 = m0 + quad * 4 + r;
                    int node = n0 + nl2;
                    if (node < N) {
                        rootOut[((size_t)k * N + node) * COUT + f] =
                            (unsigned short)f32_to_bf16_bits(aR[k][nt][r]);
                        tblOut[(size_t)node * 2 * COUT + (size_t)k * COUT + f] =
                            f32_to_fp8(aT[k][nt][r] * dvl[nl2]);
                    }
                }
            }
        }
    } else {
        floatx4 ac[2][NT] = {};
#pragma unroll
        for (int kc = 0; kc < 2; ++kc) {
            int cc = kc * 4 + quad;
            int ao = (m0 + li) * 64 + ((cc ^ am) << 3);
            short8 a0 = *(const short8*)(At + ao);
            short8 a1 = *(const short8*)(At + 4096 + ao);
#pragma unroll
            for (int nt = 0; nt < NT; ++nt) {
                int f = nt * 16 + li;
                int fc = (COUT & 15) ? ((f < COUT) ? f : (COUT - 1)) : f;
                int bo = fc * 64 + ((cc ^ (fc & 7)) << 3);
                short8 b0 = *(const short8*)(Bs + bo);
                short8 b1v = *(const short8*)(Bs + BT + bo);
                ac[0][nt] = __builtin_amdgcn_mfma_f32_16x16x32_bf16(a0, b0, ac[0][nt], 0, 0, 0);
                ac[1][nt] = __builtin_amdgcn_mfma_f32_16x16x32_bf16(a1, b1v, ac[1][nt], 0, 0, 0);
            }
        }
#pragma unroll
        for (int k = 0; k < 2; ++k) {
#pragma unroll
            for (int nt = 0; nt < NT; ++nt) {
                int f = nt * 16 + li;
                if (f >= COUT) continue;
#pragma unroll
                for (int r = 0; r < 4; ++r) {
                    int nl2 = m0 + quad * 4 + r;
                    int node = n0 + nl2;
                    if (node < N)
                        tblOut[(size_t)node * 2 * COUT + (size_t)k * COUT + f] =
                            f32_to_fp8(ac[k][nt][r] * dvl[nl2]);
                }
            }
        }
    }
}

// ---------------- final sparse aggregation: fp8 table, 2 nodes/wave, fused mean+lsm --------
template <int F>
__global__ __launch_bounds__(256) void agg_kernel(
    const unsigned char* __restrict__ h8, const int* __restrict__ row_ptr,
    const int* __restrict__ col, const float* __restrict__ dinv,
    const unsigned short* __restrict__ rootb, const float* __restrict__ bias,
    void* __restrict__ out, int N, int do_relu, int mode) {
    constexpr int FH = F / 8;
    constexpr int ROWB = 2 * F;  // interleaved row bytes (fp8)
    int wid = (blockIdx.x * blockDim.x + threadIdx.x) >> 6;
    int lane = threadIdx.x & 63;
    int half = lane >> 5;
    int l32 = lane & 31;
    int node = wid * 2 + half;
    bool valid = node < N;
    int e0 = 0, deg = 0;
    float dv = 0.f;
    if (valid) {
        e0 = row_ptr[node];
        deg = row_ptr[node + 1] - e0;
        dv = dinv[node];
    }
    const int sub = l32 >> 4;
    const int fq = l32 & 15;
    const int kk = fq >> 3;
    const int fqq = fq & 7;
    const int fqc = (fqq < FH) ? fqq : (FH - 1);
    const int foff = kk * F + fqc * 8;

    float acc[8] = {};
    for (int w0 = 0; w0 < deg; w0 += 32) {
        int mye = w0 + l32;
        int c = (mye < deg) ? col[e0 + mye] : 0;
        int nch = min(deg - w0, 32);
        for (int base = 0; base < nch; base += 16) {
            uint2 v[8];
            float wj[8];
#pragma unroll
            for (int u = 0; u < 8; ++u) {
                int j = base + u * 2 + sub;
                int cj = __shfl(c, (half << 5) | (j & 31));
                bool ok = (j < nch);
                wj[u] = ok ? 1.f : 0.f;
                int cs = ok ? cj : 0;
                v[u] = *(const uint2*)(h8 + (size_t)cs * ROWB + foff);
            }
#pragma unroll
            for (int u = 0; u < 8; ++u) {
                floatx2 f0 = __builtin_amdgcn_cvt_pk_f32_fp8(v[u].x, false);
                floatx2 f1 = __builtin_amdgcn_cvt_pk_f32_fp8(v[u].x, true);
                floatx2 f2 = __builtin_amdgcn_cvt_pk_f32_fp8(v[u].y, false);
                floatx2 f3 = __builtin_amdgcn_cvt_pk_f32_fp8(v[u].y, true);
                acc[0] += wj[u] * f0.x;
                acc[1] += wj[u] * f0.y;
                acc[2] += wj[u] * f1.x;
                acc[3] += wj[u] * f1.y;
                acc[4] += wj[u] * f2.x;
                acc[5] += wj[u] * f2.y;
                acc[6] += wj[u] * f3.x;
                acc[7] += wj[u] * f3.y;
            }
        }
    }
#pragma unroll
    for (int i = 0; i < 8; ++i) acc[i] += __shfl_xor(acc[i], 16);

    size_t oc = ((size_t)kk * N + (valid ? node : 0)) * F + fqc * 8;
    uint4 rv = *(const uint4*)(rootb + oc);
    const float* bp = bias + kk * F + fqc * 8;
    float4 b0 = *(const float4*)(bp);
    float4 b1 = *(const float4*)(bp + 4);
    const unsigned int ru[4] = {rv.x, rv.y, rv.z, rv.w};
    float res[8];
#pragma unroll
    for (int q = 0; q < 4; ++q) {
        float rlo = __uint_as_float(ru[q] << 16);
        float rhi = __uint_as_float(ru[q] & 0xffff0000u);
        float blo = (q < 2) ? ((q == 0) ? b0.x : b0.z) : ((q == 2) ? b1.x : b1.z);
        float bhi = (q < 2) ? ((q == 0) ? b0.y : b0.w) : ((q == 2) ? b1.y : b1.w);
        res[2 * q] = acc[2 * q] * dv + rlo + blo;
        res[2 * q + 1] = acc[2 * q + 1] * dv + rhi + bhi;
    }
    if (do_relu) {
#pragma unroll
        for (int i = 0; i < 8; ++i) res[i] = fmaxf(res[i], 0.f);
    }
    if (mode == 0) {
        if (sub == 0 && fqq < FH && valid) {
            size_t o = ((size_t)kk * N + node) * F + fqq * 8;
            uint4 w;
            w.x = pack_bf16x2(res[0], res[1]);
            w.y = pack_bf16x2(res[2], res[3]);
            w.z = pack_bf16x2(res[4], res[5]);
            w.w = pack_bf16x2(res[6], res[7]);
            *(uint4*)((unsigned short*)out + o) = w;
        }
    } else {
        float mres[8];
#pragma unroll
        for (int i = 0; i < 8; ++i) mres[i] = 0.5f * (res[i] + __shfl_xor(res[i], 8));
        if (mode == 1) {
            if (sub == 0 && kk == 0 && fqq < FH && valid) {
                size_t o = (size_t)node * F + fqq * 8;
                *(float4*)((float*)out + o) = make_float4(mres[0], mres[1], mres[2], mres[3]);
                *(float4*)((float*)out + o + 4) = make_float4(mres[4], mres[5], mres[6], mres[7]);
            }
        } else {
            bool act = (fqq < FH);
            float lm = -INFINITY;
            if (act) {
#pragma unroll
                for (int i = 0; i < 8; ++i) lm = fmaxf(lm, mres[i]);
            }
#pragma unroll
            for (int m = 1; m < 8; m <<= 1) lm = fmaxf(lm, __shfl_xor(lm, m));
            float ls = 0.f;
            if (act) {
#pragma unroll
                for (int i = 0; i < 8; ++i) ls += expf(mres[i] - lm);
            }
#pragma unroll
            for (int m = 1; m < 8; m <<= 1) ls += __shfl_xor(ls, m);
            float lg = lm + logf(ls);
            if (sub == 0 && kk == 0 && act && valid) {
                size_t o = (size_t)node * F + fqq * 8;
                *(float4*)((float*)out + o) =
                    make_float4(mres[0] - lg, mres[1] - lg, mres[2] - lg, mres[3] - lg);
                *(float4*)((float*)out + o + 4) =
                    make_float4(mres[4] - lg, mres[5] - lg, mres[6] - lg, mres[7] - lg);
            }
        }
    }
}

// ---------------- launch ----------------

static inline size_t align256(size_t x) { return (x + 255) & ~(size_t)255; }

extern "C" void kernel_launch(void* const* d_in, const int* in_sizes, int n_in,
                              void* d_out, int out_size, void* d_ws, size_t ws_size,
                              hipStream_t stream) {
    const float* x = (const float*)d_in[0];
    const int* ei = (const int*)d_in[1];
    const float* w1_init = (const float*)d_in[2];
    const float* w1 = (const float*)d_in[3];
    const float* v1 = (const float*)d_in[4];
    const float* b1 = (const float*)d_in[5];
    const float* w2_init = (const float*)d_in[6];
    const float* w2 = (const float*)d_in[7];
    const float* v2 = (const float*)d_in[8];
    const float* b2 = (const float*)d_in[9];

    const int N = in_sizes[0] / F_IN;
    const int E = in_sizes[1] / 2;
    const int* src = ei;
    const int* dst = ei + E;

    char* p = (char*)d_ws;
    auto take = [&](size_t bytes) {
        char* r = p;
        p += align256(bytes);
        return r;
    };
    float* dinv = (float*)take((size_t)N * 4);
    int* row_ptr = (int*)take((size_t)(N + 1) * 4);
    int* tileSums = (int*)take(256 * 4);
    int* counts = (int*)take((size_t)256 * NBLK_CNT * 4);
    int* scanned = (int*)take((size_t)256 * NBLK_CNT * 4);
    unsigned int* pairs = (unsigned int*)take((size_t)E * 4);
    int* col = (int*)take((size_t)E * 4);
    unsigned short* v1t = (unsigned short*)take((size_t)2 * 64 * 128 * 2);
    unsigned short* w1it = (unsigned short*)take((size_t)2 * 64 * 128 * 2);
    unsigned short* w1t = (unsigned short*)take((size_t)2 * 64 * 64 * 2);
    unsigned short* v2t = (unsigned short*)take((size_t)2 * 40 * 64 * 2);
    unsigned short* w2it = (unsigned short*)take((size_t)2 * 40 * 64 * 2);
    unsigned short* w2t = (unsigned short*)take((size_t)2 * 40 * 64 * 2);
    unsigned short* rootb = (unsigned short*)take((size_t)K_STACKS * N * HID * 2);
    unsigned short* root2 = (unsigned short*)take((size_t)K_STACKS * N * NCLS * 2);
    unsigned char* tblA = (unsigned char*)take((size_t)K_STACKS * N * HID);
    unsigned char* tblB = (unsigned char*)take((size_t)K_STACKS * N * HID);

    const int TB = 256;
    const int nCnt = 256 * NBLK_CNT;           // 65536
    const int nScanBlocks = nCnt / SCAN_TILE;  // 64
    const int nBuckets = (N + 255) / 256;      // 196
    const int ntiles = (N + 63) / 64;          // 782

    hipMemsetAsync(tileSums, 0, 256, stream);
    count_kernel<<<NBLK_CNT, 256, 0, stream>>>(dst, counts, tileSums, E);
    scan_phase3_excl<<<nScanBlocks, 256, 0, stream>>>(counts, tileSums, scanned, nCnt);
    bucket_scatter_kernel<<<NBLK_CNT, 256, 0, stream>>>(src, dst, scanned, pairs, E);
    csr_build_kernel<<<nBuckets, 256, 0, stream>>>(pairs, scanned, row_ptr, dinv, col, N, E);

    wt_all_kernel<<<(56320 + TB - 1) / TB, TB, 0, stream>>>(v1, w1_init, w1, v2, w2_init, w2,
                                                            v1t, w1it, w1t, v2t, w2it, w2t);

    const int agg_blocks = ((N + 1) / 2 + 3) / 4;  // 2 nodes per wave, 4 waves per block

    // ----- layer 1: x -> root1 + table0; fused {agg+relu} x {gemm w1} -> table1 -----
    gemm12_kernel<<<ntiles, 256, 0, stream>>>(x, v1t, w1it, rootb, tblA, dinv, N);
    agg_gemm_kernel<HID, HID, 0><<<ntiles, 256, 0, stream>>>(
        tblA, row_ptr, col, dinv, rootb, b1, w1t, nullptr, nullptr, tblB, N);

    // ----- layer 2 entry: fused {agg+relu+mean} x {gemm v2 & w2_init} -> root2 + table2 -----
    agg_gemm_kernel<HID, NCLS, 1><<<ntiles, 256, 0, stream>>>(
        tblB, row_ptr, col, dinv, rootb, b1, v2t, w2it, root2, tblA, N);

    // ----- layer 2, t=1: fused {agg (no relu)} x {gemm w2} -> table3 -----
    agg_gemm_kernel<NCLS, NCLS, 2><<<ntiles, 256, 0, stream>>>(
        tblA, row_ptr, col, dinv, root2, b2, w2t, nullptr, nullptr, tblB, N);

    // ----- final aggregation: mean over k + log_softmax -----
    agg_kernel<NCLS><<<agg_blocks, 256, 0, stream>>>(tblB, row_ptr, col, dinv, root2, b2,
                                                     (float*)d_out, N, 0, 2);
}

// Round 2
// 274.400 us; speedup vs baseline: 1.1017x; 1.1017x over previous
//
#include <hip/hip_runtime.h>
#include <hip/hip_bf16.h>
#include <math.h>

#define N_NODES 50000
#define F_IN 128
#define HID 64
#define NCLS 40
#define K_STACKS 2
#define SCAN_TILE 1024
#define NBLK_CNT 256  // radix blocks; 256 buckets of 256 node-ids (N=50000 -> 196 used)

typedef __attribute__((ext_vector_type(8))) short short8;
typedef __attribute__((ext_vector_type(4))) float floatx4;
typedef __attribute__((ext_vector_type(2))) float floatx2;

__device__ __forceinline__ unsigned int f32_to_bf16_bits(float f) {
    unsigned int u = __float_as_uint(f);
    return (u + 0x7fffu + ((u >> 16) & 1u)) >> 16;  // RNE
}
__device__ __forceinline__ unsigned int pack_bf16x2(float a, float b) {
    return f32_to_bf16_bits(a) | (f32_to_bf16_bits(b) << 16);
}
__device__ __forceinline__ unsigned char f32_to_fp8(float v) {
    int pk = __builtin_amdgcn_cvt_pk_fp8_f32(v, v, 0, false);  // OCP e4m3 on gfx950
    return (unsigned char)(pk & 0xff);
}

// ---------------- CSR build via radix bucketing (dst>>8) ----------------
// NOTE: packing src into 16 bits requires N <= 65536 (here N=50000).

__global__ __launch_bounds__(256) void count_kernel(const int* __restrict__ dst,
                                                    int* __restrict__ counts,
                                                    int* __restrict__ tileSums, int E) {
    __shared__ int hist[256];
    __shared__ int ts[64];
    int blk = blockIdx.x, t = threadIdx.x;
    hist[t] = 0;
    if (t < 64) ts[t] = 0;
    __syncthreads();
    int chunk = (E + NBLK_CNT - 1) / NBLK_CNT;
    int s = blk * chunk, e = min(E, s + chunk);
    for (int i = s + t; i < e; i += 256) atomicAdd(&hist[dst[i] >> 8], 1);
    __syncthreads();
    counts[t * NBLK_CNT + blk] = hist[t];  // bucket-major
    atomicAdd(&ts[t >> 2], hist[t]);
    __syncthreads();
    if (t < 64) atomicAdd(&tileSums[t], ts[t]);
}

__global__ __launch_bounds__(256) void scan_phase3_excl(const int* __restrict__ in,
                                                        const int* __restrict__ tileSums,
                                                        int* __restrict__ out, int n) {
    __shared__ int lds[256];
    __shared__ int tsum[64];
    int b = blockIdx.x, t = threadIdx.x;
    if (t < 64) tsum[t] = tileSums[t];
    int base = b * SCAN_TILE + t * 4;
    int e[4];
    int s = 0;
#pragma unroll
    for (int i = 0; i < 4; ++i) {
        e[i] = (base + i < n) ? in[base + i] : 0;
        s += e[i];
    }
    lds[t] = s;
    __syncthreads();
    int v = s;
    for (int off = 1; off < 256; off <<= 1) {
        int add = (t >= off) ? lds[t - off] : 0;
        __syncthreads();
        v += add;
        lds[t] = v;
        __syncthreads();
    }
    int toff = 0;
    for (int i = 0; i < b; ++i) toff += tsum[i];
    int run = (t == 0 ? 0 : lds[t - 1]) + toff;
#pragma unroll
    for (int i = 0; i < 4; ++i) {
        if (base + i < n) {
            out[base + i] = run;
            run += e[i];
        }
    }
}

__global__ __launch_bounds__(256) void bucket_scatter_kernel(const int* __restrict__ src,
                                                             const int* __restrict__ dst,
                                                             const int* __restrict__ scanned,
                                                             unsigned int* __restrict__ pairs,
                                                             int E) {
    __shared__ int cur[256];
    int blk = blockIdx.x, t = threadIdx.x;
    cur[t] = scanned[t * NBLK_CNT + blk];
    __syncthreads();
    int chunk = (E + NBLK_CNT - 1) / NBLK_CNT;
    int s0 = blk * chunk, e0 = min(E, s0 + chunk);
    for (int i = s0 + t; i < e0; i += 256) {
        int d = dst[i];
        int pos = atomicAdd(&cur[d >> 8], 1);
        pairs[pos] = (unsigned int)src[i] | ((unsigned int)(d & 255) << 16);
    }
}

__global__ __launch_bounds__(256) void csr_build_kernel(const unsigned int* __restrict__ pairs,
                                                        const int* __restrict__ scanned,
                                                        int* __restrict__ row_ptr,
                                                        float* __restrict__ dinv,
                                                        int* __restrict__ col, int N, int E) {
    __shared__ int degl[256], lds[256], curl[256], sb[2];
    int b = blockIdx.x, t = threadIdx.x;
    if (t == 0) {
        sb[0] = scanned[b * NBLK_CNT];
        sb[1] = (b + 1 < 256) ? scanned[(b + 1) * NBLK_CNT] : E;
    }
    degl[t] = 0;
    __syncthreads();
    int bstart = sb[0], bend = sb[1];
    for (int e = bstart + t; e < bend; e += 256) {
        atomicAdd(&degl[(pairs[e] >> 16) & 255], 1);
    }
    __syncthreads();
    int d = degl[t];
    lds[t] = d;
    __syncthreads();
    int v = d;
    for (int off = 1; off < 256; off <<= 1) {
        int add = (t >= off) ? lds[t - off] : 0;
        __syncthreads();
        v += add;
        lds[t] = v;
        __syncthreads();
    }
    int excl = v - d;
    int node = b * 256 + t;
    if (node <= N) row_ptr[node] = bstart + excl;
    if (node < N) dinv[node] = (d > 0) ? (1.0f / sqrtf((float)d)) : 0.0f;
    curl[t] = excl;
    __syncthreads();
    for (int e = bstart + t; e < bend; e += 256) {
        unsigned int p = pairs[e];
        int ln = (p >> 16) & 255;
        int pos = atomicAdd(&curl[ln], 1);
        col[bstart + pos] = (int)(p & 0xffffu);
    }
}

// ---------------- fused weight pre-transpose: [k][C][F] fp32 -> [k][F][CP] bf16 ----------
__device__ __forceinline__ void wt_one(const float* __restrict__ in,
                                       unsigned short* __restrict__ out, int li, int C, int F,
                                       int CP) {
    int k = li / (F * CP);
    int r = li - k * F * CP;
    int f = r / CP;
    int c = r - f * CP;
    out[li] = (c < C) ? (unsigned short)f32_to_bf16_bits(in[((size_t)k * C + c) * F + f]) : 0;
}

__global__ void wt_all_kernel(const float* v1, const float* w1i, const float* w1,
                              const float* v2, const float* w2i, const float* w2,
                              unsigned short* v1t, unsigned short* w1it, unsigned short* w1t,
                              unsigned short* v2t, unsigned short* w2it, unsigned short* w2t) {
    int i = blockIdx.x * blockDim.x + threadIdx.x;
    if (i < 16384) wt_one(v1, v1t, i, 128, 64, 128);
    else if (i < 32768) wt_one(w1i, w1it, i - 16384, 128, 64, 128);
    else if (i < 40960) wt_one(w1, w1t, i - 32768, 64, 64, 64);
    else if (i < 46080) wt_one(v2, v2t, i - 40960, 64, 40, 64);
    else if (i < 51200) wt_one(w2i, w2it, i - 46080, 64, 40, 64);
    else if (i < 56320) wt_one(w2, w2t, i - 51200, 40, 40, 64);
}

// ---------------- staging helpers ----------------
template <int CINP>
__device__ __forceinline__ void stage_A(const void* A, unsigned short* At, size_t abase,
                                        int n0, int t, int N, int CREAL, int a_bf16,
                                        int stride) {
    constexpr int CP8 = CINP / 8;
    constexpr int MS = CP8 - 1;
    constexpr int SH = (CP8 == 16) ? 4 : 3;
    for (int i = t; i < 64 * CP8; i += stride) {
        int n = i >> SH;
        int c = i & MS;
        uint4 w = make_uint4(0u, 0u, 0u, 0u);
        int gn = n0 + n;
        if (gn < N && c * 8 < CREAL) {
            if (a_bf16) {
                w = *(const uint4*)((const unsigned short*)A + abase + (size_t)gn * CREAL + c * 8);
            } else {
                const float* srcp = (const float*)A + abase + (size_t)gn * CREAL + c * 8;
                float4 f0 = *(const float4*)(srcp);
                float4 f1 = *(const float4*)(srcp + 4);
                w.x = pack_bf16x2(f0.x, f0.y);
                w.y = pack_bf16x2(f0.z, f0.w);
                w.z = pack_bf16x2(f1.x, f1.y);
                w.w = pack_bf16x2(f1.z, f1.w);
            }
        }
        *(uint4*)(At + n * CINP + ((c ^ (n & MS)) << 3)) = w;
    }
}

template <int CINP>
__device__ __forceinline__ void stage_B(const unsigned short* Bk, unsigned short* Bs, int t,
                                        int COUT, int stride) {
    constexpr int CP8 = CINP / 8;
    constexpr int MS = CP8 - 1;
    constexpr int SH = (CP8 == 16) ? 4 : 3;
    for (int i = t; i < COUT * CP8; i += stride) {
        int f = i >> SH;
        int c = i & MS;
        uint4 w = *(const uint4*)(Bk + f * CINP + c * 8);
        *(uint4*)(Bs + f * CINP + ((c ^ (f & MS)) << 3)) = w;
    }
}

// ---------------- layer-1 entry GEMM (per-k grid, verified round-0 form) ----------------
// shared A -> root (bf16 std [k][N][COUT]) + table (fp8 inter [node][k][COUT], dinv-scaled)
template <int CINP>
__global__ __launch_bounds__(256) void gemm2_mfma(
    const void* __restrict__ A, const unsigned short* __restrict__ Bt1,
    const unsigned short* __restrict__ Bt2, unsigned short* __restrict__ out1,
    unsigned char* __restrict__ out2, const float* __restrict__ scale, int N, int COUT,
    int CREAL, int a_bf16) {
    constexpr int MS = CINP / 8 - 1;
    __shared__ __align__(16) unsigned short At[64 * CINP];
    __shared__ __align__(16) unsigned short Bs1[64 * CINP];
    __shared__ __align__(16) unsigned short Bs2[64 * CINP];

    const int k = blockIdx.y;
    const int n0 = blockIdx.x * 64;
    const int t = threadIdx.x;
    stage_A<CINP>(A, At, (size_t)0, n0, t, N, CREAL, a_bf16, 256);
    stage_B<CINP>(Bt1 + (size_t)k * COUT * CINP, Bs1, t, COUT, 256);
    stage_B<CINP>(Bt2 + (size_t)k * COUT * CINP, Bs2, t, COUT, 256);
    __syncthreads();

    const int lane = t & 63;
    const int wv = t >> 6;
    const int quad = lane >> 4;
    const int li = lane & 15;
    const int m0 = wv * 16;

    floatx4 acc1[4] = {{0.f, 0.f, 0.f, 0.f}, {0.f, 0.f, 0.f, 0.f},
                       {0.f, 0.f, 0.f, 0.f}, {0.f, 0.f, 0.f, 0.f}};
    floatx4 acc2[4] = {{0.f, 0.f, 0.f, 0.f}, {0.f, 0.f, 0.f, 0.f},
                       {0.f, 0.f, 0.f, 0.f}, {0.f, 0.f, 0.f, 0.f}};
    const int am = (m0 + li) & MS;
#pragma unroll
    for (int kc = 0; kc < CINP / 32; ++kc) {
        int cc = kc * 4 + quad;
        short8 a = *(const short8*)(At + (m0 + li) * CINP + ((cc ^ am) << 3));
#pragma unroll
        for (int nt = 0; nt < 4; ++nt) {
            if (nt * 16 < COUT) {
                int f = nt * 16 + li;
                int bo = f * CINP + ((cc ^ (f & MS)) << 3);
                short8 b1 = *(const short8*)(Bs1 + bo);
                short8 b2 = *(const short8*)(Bs2 + bo);
                acc1[nt] = __builtin_amdgcn_mfma_f32_16x16x32_bf16(a, b1, acc1[nt], 0, 0, 0);
                acc2[nt] = __builtin_amdgcn_mfma_f32_16x16x32_bf16(a, b2, acc2[nt], 0, 0, 0);
            }
        }
    }

    float sc[4];
#pragma unroll
    for (int r = 0; r < 4; ++r) {
        int node = n0 + m0 + quad * 4 + r;
        sc[r] = (node < N) ? scale[node] : 1.f;
    }
#pragma unroll
    for (int nt = 0; nt < 4; ++nt) {
        if (nt * 16 >= COUT) continue;
        int f = nt * 16 + li;
        if (f >= COUT) continue;
#pragma unroll
        for (int r = 0; r < 4; ++r) {
            int node = n0 + m0 + quad * 4 + r;
            if (node < N) {
                out1[((size_t)k * N + node) * COUT + f] =
                    (unsigned short)f32_to_bf16_bits(acc1[nt][r]);
                out2[(size_t)node * 2 * COUT + (size_t)k * COUT + f] =
                    f32_to_fp8(acc2[nt][r] * sc[r]);
            }
        }
    }
}

// ---------------- fused aggregation + GEMM (512 threads / 8 waves) ----------------
// Phase 1: per-wave gather/aggregate (2 nodes per pass, 4 passes -> 8 rows/wave); epilogue
// (dinv scale + root + bias [+relu][+mean-over-k]) writes straight into swizzled LDS A-tile.
// Phase 2: MFMA over the LDS tile; waves 0-3 compute k=0, waves 4-7 compute k=1.
// FMODE 0: per-k A, relu       (layer 1, t=1)    COUT=64, 1 B/k
// FMODE 1: mean-over-k A, relu (layer 2 entry)   COUT=40, 2 B/k  (root out + table out)
// FMODE 2: per-k A, no relu    (layer 2, t=1)    COUT=40, 1 B/k
template <int F, int COUT, int FMODE>
__global__ __launch_bounds__(512) void agg_gemm_kernel(
    const unsigned char* __restrict__ h8, const int* __restrict__ row_ptr,
    const int* __restrict__ col, const float* __restrict__ dinv,
    const unsigned short* __restrict__ rootb, const float* __restrict__ bias,
    const unsigned short* __restrict__ Bt1, const unsigned short* __restrict__ Bt2,
    unsigned short* __restrict__ rootOut, unsigned char* __restrict__ tblOut, int N) {
    constexpr int NA = (FMODE == 1) ? 1 : 2;
    constexpr int NB = (FMODE == 1) ? 4 : 2;
    constexpr int BT = COUT * 64;
    constexpr int NT = (COUT + 15) / 16;
    constexpr int FH = F / 8;
    constexpr int ROWB = 2 * F;
    __shared__ __align__(16) unsigned short At[NA * 64 * 64];
    __shared__ __align__(16) unsigned short Bs[NB * BT];
    __shared__ int rp[65];
    __shared__ float dvl[64];

    const int n0 = blockIdx.x * 64;
    const int t = threadIdx.x;

    stage_B<64>(Bt1, Bs, t, COUT, 512);
    stage_B<64>(Bt1 + (size_t)COUT * 64, Bs + BT, t, COUT, 512);
    if constexpr (FMODE == 1) {
        stage_B<64>(Bt2, Bs + 2 * BT, t, COUT, 512);
        stage_B<64>(Bt2 + (size_t)COUT * 64, Bs + 3 * BT, t, COUT, 512);
    }
    if (t < 65) rp[t] = row_ptr[min(n0 + t, N)];
    if (t < 64) dvl[t] = (n0 + t < N) ? dinv[n0 + t] : 0.f;
    __syncthreads();

    const int lane = t & 63;
    const int wv = t >> 6;  // 0..7
    const int half = lane >> 5;
    const int l32 = lane & 31;
    const int sub = l32 >> 4;
    const int fq = l32 & 15;
    const int kk = fq >> 3;
    const int fqq = fq & 7;
    const int fqc = (fqq < FH) ? fqq : (FH - 1);
    const int foff = kk * F + fqc * 8;

    // ---- phase 1: each wave aggregates 8 rows (4 passes x 2 nodes) into LDS A ----
#pragma unroll 1
    for (int p = 0; p < 4; ++p) {
        const int nl = wv * 8 + p * 2 + half;
        const int node = n0 + nl;
        const bool valid = node < N;
        const int e0 = rp[nl];
        const int deg = rp[nl + 1] - e0;
        const float dv = dvl[nl];
        float acc[8] = {};
        for (int w0 = 0; w0 < deg; w0 += 32) {
            int mye = w0 + l32;
            int c = (mye < deg) ? col[e0 + mye] : 0;
            int nch = min(deg - w0, 32);
            for (int base = 0; base < nch; base += 16) {
                uint2 v[8];
                float wj[8];
#pragma unroll
                for (int u = 0; u < 8; ++u) {
                    int j = base + u * 2 + sub;
                    int cj = __shfl(c, (half << 5) | (j & 31));
                    bool ok = (j < nch);
                    wj[u] = ok ? 1.f : 0.f;
                    int cs = ok ? cj : 0;
                    v[u] = *(const uint2*)(h8 + (size_t)cs * ROWB + foff);
                }
#pragma unroll
                for (int u = 0; u < 8; ++u) {
                    floatx2 f0 = __builtin_amdgcn_cvt_pk_f32_fp8(v[u].x, false);
                    floatx2 f1 = __builtin_amdgcn_cvt_pk_f32_fp8(v[u].x, true);
                    floatx2 f2 = __builtin_amdgcn_cvt_pk_f32_fp8(v[u].y, false);
                    floatx2 f3 = __builtin_amdgcn_cvt_pk_f32_fp8(v[u].y, true);
                    acc[0] += wj[u] * f0.x;
                    acc[1] += wj[u] * f0.y;
                    acc[2] += wj[u] * f1.x;
                    acc[3] += wj[u] * f1.y;
                    acc[4] += wj[u] * f2.x;
                    acc[5] += wj[u] * f2.y;
                    acc[6] += wj[u] * f3.x;
                    acc[7] += wj[u] * f3.y;
                }
            }
        }
#pragma unroll
        for (int i = 0; i < 8; ++i) acc[i] += __shfl_xor(acc[i], 16);

        size_t oc = ((size_t)kk * N + (valid ? node : 0)) * F + fqc * 8;
        uint4 rv = *(const uint4*)(rootb + oc);
        const float* bp = bias + kk * F + fqc * 8;
        float4 b0 = *(const float4*)(bp);
        float4 b1_ = *(const float4*)(bp + 4);
        const unsigned int ru[4] = {rv.x, rv.y, rv.z, rv.w};
        float res[8];
#pragma unroll
        for (int q = 0; q < 4; ++q) {
            float rlo = __uint_as_float(ru[q] << 16);
            float rhi = __uint_as_float(ru[q] & 0xffff0000u);
            float blo = (q < 2) ? ((q == 0) ? b0.x : b0.z) : ((q == 2) ? b1_.x : b1_.z);
            float bhi = (q < 2) ? ((q == 0) ? b0.y : b0.w) : ((q == 2) ? b1_.y : b1_.w);
            res[2 * q] = acc[2 * q] * dv + rlo + blo;
            res[2 * q + 1] = acc[2 * q + 1] * dv + rhi + bhi;
        }
        if constexpr (FMODE != 2) {
#pragma unroll
            for (int i = 0; i < 8; ++i) res[i] = fmaxf(res[i], 0.f);
        }
        if constexpr (FMODE == 1) {
            float mres[8];
#pragma unroll
            for (int i = 0; i < 8; ++i) mres[i] = 0.5f * (res[i] + __shfl_xor(res[i], 8));
            if (sub == 0 && kk == 0) {
                uint4 w;
                w.x = pack_bf16x2(mres[0], mres[1]);
                w.y = pack_bf16x2(mres[2], mres[3]);
                w.z = pack_bf16x2(mres[4], mres[5]);
                w.w = pack_bf16x2(mres[6], mres[7]);
                *(uint4*)(At + nl * 64 + ((fqq ^ (nl & 7)) << 3)) = w;
            }
        } else {
            if (sub == 0) {
                uint4 w = make_uint4(0u, 0u, 0u, 0u);
                if (fqq < FH) {
                    w.x = pack_bf16x2(res[0], res[1]);
                    w.y = pack_bf16x2(res[2], res[3]);
                    w.z = pack_bf16x2(res[4], res[5]);
                    w.w = pack_bf16x2(res[6], res[7]);
                }
                *(uint4*)(At + kk * 4096 + nl * 64 + ((fqq ^ (nl & 7)) << 3)) = w;
            }
        }
    }
    __syncthreads();

    // ---- phase 2: MFMA over LDS tile(s); waves 0-3 -> k=0, waves 4-7 -> k=1 ----
    const int quad = lane >> 4;
    const int li = lane & 15;
    const int kSel = wv >> 2;
    const int m0 = (wv & 3) * 16;
    const int am = (m0 + li) & 7;

    if constexpr (FMODE == 1) {
        floatx4 aR[NT] = {};
        floatx4 aT[NT] = {};
#pragma unroll
        for (int kc = 0; kc < 2; ++kc) {
            int cc = kc * 4 + quad;
            short8 a = *(const short8*)(At + (m0 + li) * 64 + ((cc ^ am) << 3));
#pragma unroll
            for (int nt = 0; nt < NT; ++nt) {
                int f = nt * 16 + li;
                int fc = (COUT & 15) ? ((f < COUT) ? f : (COUT - 1)) : f;
                int bo = fc * 64 + ((cc ^ (fc & 7)) << 3);
                short8 bR = *(const short8*)(Bs + kSel * BT + bo);
                short8 bT = *(const short8*)(Bs + (2 + kSel) * BT + bo);
                aR[nt] = __builtin_amdgcn_mfma_f32_16x16x32_bf16(a, bR, aR[nt], 0, 0, 0);
                aT[nt] = __builtin_amdgcn_mfma_f32_16x16x32_bf16(a, bT, aT[nt], 0, 0, 0);
            }
        }
#pragma unroll
        for (int nt = 0; nt < NT; ++nt) {
            int f = nt * 16 + li;
            if (f >= COUT) continue;
#pragma unroll
            for (int r = 0; r < 4; ++r) {
                int nl2 = m0 + quad * 4 + r;
                int node = n0 + nl2;
                if (node < N) {
                    rootOut[((size_t)kSel * N + node) * COUT + f] =
                        (unsigned short)f32_to_bf16_bits(aR[nt][r]);
                    tblOut[(size_t)node * 2 * COUT + (size_t)kSel * COUT + f] =
                        f32_to_fp8(aT[nt][r] * dvl[nl2]);
                }
            }
        }
    } else {
        floatx4 ac[NT] = {};
#pragma unroll
        for (int kc = 0; kc < 2; ++kc) {
            int cc = kc * 4 + quad;
            short8 a = *(const short8*)(At + kSel * 4096 + (m0 + li) * 64 + ((cc ^ am) << 3));
#pragma unroll
            for (int nt = 0; nt < NT; ++nt) {
                int f = nt * 16 + li;
                int fc = (COUT & 15) ? ((f < COUT) ? f : (COUT - 1)) : f;
                int bo = fc * 64 + ((cc ^ (fc & 7)) << 3);
                short8 b = *(const short8*)(Bs + kSel * BT + bo);
                ac[nt] = __builtin_amdgcn_mfma_f32_16x16x32_bf16(a, b, ac[nt], 0, 0, 0);
            }
        }
#pragma unroll
        for (int nt = 0; nt < NT; ++nt) {
            int f = nt * 16 + li;
            if (f >= COUT) continue;
#pragma unroll
            for (int r = 0; r < 4; ++r) {
                int nl2 = m0 + quad * 4 + r;
                int node = n0 + nl2;
                if (node < N)
                    tblOut[(size_t)node * 2 * COUT + (size_t)kSel * COUT + f] =
                        f32_to_fp8(ac[nt][r] * dvl[nl2]);
            }
        }
    }
}

// ---------------- final sparse aggregation: fp8 table, 2 nodes/wave, fused mean+lsm --------
template <int F>
__global__ __launch_bounds__(256) void agg_kernel(
    const unsigned char* __restrict__ h8, const int* __restrict__ row_ptr,
    const int* __restrict__ col, const float* __restrict__ dinv,
    const unsigned short* __restrict__ rootb, const float* __restrict__ bias,
    void* __restrict__ out, int N, int do_relu, int mode) {
    constexpr int FH = F / 8;
    constexpr int ROWB = 2 * F;  // interleaved row bytes (fp8)
    int wid = (blockIdx.x * blockDim.x + threadIdx.x) >> 6;
    int lane = threadIdx.x & 63;
    int half = lane >> 5;
    int l32 = lane & 31;
    int node = wid * 2 + half;
    bool valid = node < N;
    int e0 = 0, deg = 0;
    float dv = 0.f;
    if (valid) {
        e0 = row_ptr[node];
        deg = row_ptr[node + 1] - e0;
        dv = dinv[node];
    }
    const int sub = l32 >> 4;
    const int fq = l32 & 15;
    const int kk = fq >> 3;
    const int fqq = fq & 7;
    const int fqc = (fqq < FH) ? fqq : (FH - 1);
    const int foff = kk * F + fqc * 8;

    float acc[8] = {};
    for (int w0 = 0; w0 < deg; w0 += 32) {
        int mye = w0 + l32;
        int c = (mye < deg) ? col[e0 + mye] : 0;
        int nch = min(deg - w0, 32);
        for (int base = 0; base < nch; base += 16) {
            uint2 v[8];
            float wj[8];
#pragma unroll
            for (int u = 0; u < 8; ++u) {
                int j = base + u * 2 + sub;
                int cj = __shfl(c, (half << 5) | (j & 31));
                bool ok = (j < nch);
                wj[u] = ok ? 1.f : 0.f;
                int cs = ok ? cj : 0;
                v[u] = *(const uint2*)(h8 + (size_t)cs * ROWB + foff);
            }
#pragma unroll
            for (int u = 0; u < 8; ++u) {
                floatx2 f0 = __builtin_amdgcn_cvt_pk_f32_fp8(v[u].x, false);
                floatx2 f1 = __builtin_amdgcn_cvt_pk_f32_fp8(v[u].x, true);
                floatx2 f2 = __builtin_amdgcn_cvt_pk_f32_fp8(v[u].y, false);
                floatx2 f3 = __builtin_amdgcn_cvt_pk_f32_fp8(v[u].y, true);
                acc[0] += wj[u] * f0.x;
                acc[1] += wj[u] * f0.y;
                acc[2] += wj[u] * f1.x;
                acc[3] += wj[u] * f1.y;
                acc[4] += wj[u] * f2.x;
                acc[5] += wj[u] * f2.y;
                acc[6] += wj[u] * f3.x;
                acc[7] += wj[u] * f3.y;
            }
        }
    }
#pragma unroll
    for (int i = 0; i < 8; ++i) acc[i] += __shfl_xor(acc[i], 16);

    size_t oc = ((size_t)kk * N + (valid ? node : 0)) * F + fqc * 8;
    uint4 rv = *(const uint4*)(rootb + oc);
    const float* bp = bias + kk * F + fqc * 8;
    float4 b0 = *(const float4*)(bp);
    float4 b1 = *(const float4*)(bp + 4);
    const unsigned int ru[4] = {rv.x, rv.y, rv.z, rv.w};
    float res[8];
#pragma unroll
    for (int q = 0; q < 4; ++q) {
        float rlo = __uint_as_float(ru[q] << 16);
        float rhi = __uint_as_float(ru[q] & 0xffff0000u);
        float blo = (q < 2) ? ((q == 0) ? b0.x : b0.z) : ((q == 2) ? b1.x : b1.z);
        float bhi = (q < 2) ? ((q == 0) ? b0.y : b0.w) : ((q == 2) ? b1.y : b1.w);
        res[2 * q] = acc[2 * q] * dv + rlo + blo;
        res[2 * q + 1] = acc[2 * q + 1] * dv + rhi + bhi;
    }
    if (do_relu) {
#pragma unroll
        for (int i = 0; i < 8; ++i) res[i] = fmaxf(res[i], 0.f);
    }
    if (mode == 0) {
        if (sub == 0 && fqq < FH && valid) {
            size_t o = ((size_t)kk * N + node) * F + fqq * 8;
            uint4 w;
            w.x = pack_bf16x2(res[0], res[1]);
            w.y = pack_bf16x2(res[2], res[3]);
            w.z = pack_bf16x2(res[4], res[5]);
            w.w = pack_bf16x2(res[6], res[7]);
            *(uint4*)((unsigned short*)out + o) = w;
        }
    } else {
        float mres[8];
#pragma unroll
        for (int i = 0; i < 8; ++i) mres[i] = 0.5f * (res[i] + __shfl_xor(res[i], 8));
        if (mode == 1) {
            if (sub == 0 && kk == 0 && fqq < FH && valid) {
                size_t o = (size_t)node * F + fqq * 8;
                *(float4*)((float*)out + o) = make_float4(mres[0], mres[1], mres[2], mres[3]);
                *(float4*)((float*)out + o + 4) = make_float4(mres[4], mres[5], mres[6], mres[7]);
            }
        } else {
            bool act = (fqq < FH);
            float lm = -INFINITY;
            if (act) {
#pragma unroll
                for (int i = 0; i < 8; ++i) lm = fmaxf(lm, mres[i]);
            }
#pragma unroll
            for (int m = 1; m < 8; m <<= 1) lm = fmaxf(lm, __shfl_xor(lm, m));
            float ls = 0.f;
            if (act) {
#pragma unroll
                for (int i = 0; i < 8; ++i) ls += expf(mres[i] - lm);
            }
#pragma unroll
            for (int m = 1; m < 8; m <<= 1) ls += __shfl_xor(ls, m);
            float lg = lm + logf(ls);
            if (sub == 0 && kk == 0 && act && valid) {
                size_t o = (size_t)node * F + fqq * 8;
                *(float4*)((float*)out + o) =
                    make_float4(mres[0] - lg, mres[1] - lg, mres[2] - lg, mres[3] - lg);
                *(float4*)((float*)out + o + 4) =
                    make_float4(mres[4] - lg, mres[5] - lg, mres[6] - lg, mres[7] - lg);
            }
        }
    }
}

// ---------------- launch ----------------

static inline size_t align256(size_t x) { return (x + 255) & ~(size_t)255; }

extern "C" void kernel_launch(void* const* d_in, const int* in_sizes, int n_in,
                              void* d_out, int out_size, void* d_ws, size_t ws_size,
                              hipStream_t stream) {
    const float* x = (const float*)d_in[0];
    const int* ei = (const int*)d_in[1];
    const float* w1_init = (const float*)d_in[2];
    const float* w1 = (const float*)d_in[3];
    const float* v1 = (const float*)d_in[4];
    const float* b1 = (const float*)d_in[5];
    const float* w2_init = (const float*)d_in[6];
    const float* w2 = (const float*)d_in[7];
    const float* v2 = (const float*)d_in[8];
    const float* b2 = (const float*)d_in[9];

    const int N = in_sizes[0] / F_IN;
    const int E = in_sizes[1] / 2;
    const int* src = ei;
    const int* dst = ei + E;

    char* p = (char*)d_ws;
    auto take = [&](size_t bytes) {
        char* r = p;
        p += align256(bytes);
        return r;
    };
    float* dinv = (float*)take((size_t)N * 4);
    int* row_ptr = (int*)take((size_t)(N + 1) * 4);
    int* tileSums = (int*)take(256 * 4);
    int* counts = (int*)take((size_t)256 * NBLK_CNT * 4);
    int* scanned = (int*)take((size_t)256 * NBLK_CNT * 4);
    unsigned int* pairs = (unsigned int*)take((size_t)E * 4);
    int* col = (int*)take((size_t)E * 4);
    unsigned short* v1t = (unsigned short*)take((size_t)2 * 64 * 128 * 2);
    unsigned short* w1it = (unsigned short*)take((size_t)2 * 64 * 128 * 2);
    unsigned short* w1t = (unsigned short*)take((size_t)2 * 64 * 64 * 2);
    unsigned short* v2t = (unsigned short*)take((size_t)2 * 40 * 64 * 2);
    unsigned short* w2it = (unsigned short*)take((size_t)2 * 40 * 64 * 2);
    unsigned short* w2t = (unsigned short*)take((size_t)2 * 40 * 64 * 2);
    unsigned short* rootb = (unsigned short*)take((size_t)K_STACKS * N * HID * 2);
    unsigned short* root2 = (unsigned short*)take((size_t)K_STACKS * N * NCLS * 2);
    unsigned char* tblA = (unsigned char*)take((size_t)K_STACKS * N * HID);
    unsigned char* tblB = (unsigned char*)take((size_t)K_STACKS * N * HID);

    const int TB = 256;
    const int nCnt = 256 * NBLK_CNT;           // 65536
    const int nScanBlocks = nCnt / SCAN_TILE;  // 64
    const int nBuckets = (N + 255) / 256;      // 196
    const int ntiles = (N + 63) / 64;          // 782

    hipMemsetAsync(tileSums, 0, 256, stream);
    count_kernel<<<NBLK_CNT, 256, 0, stream>>>(dst, counts, tileSums, E);
    scan_phase3_excl<<<nScanBlocks, 256, 0, stream>>>(counts, tileSums, scanned, nCnt);
    bucket_scatter_kernel<<<NBLK_CNT, 256, 0, stream>>>(src, dst, scanned, pairs, E);
    csr_build_kernel<<<nBuckets, 256, 0, stream>>>(pairs, scanned, row_ptr, dinv, col, N, E);

    wt_all_kernel<<<(56320 + TB - 1) / TB, TB, 0, stream>>>(v1, w1_init, w1, v2, w2_init, w2,
                                                            v1t, w1it, w1t, v2t, w2it, w2t);

    dim3 ggrid(ntiles, K_STACKS);
    const int agg_blocks = ((N + 1) / 2 + 3) / 4;  // 2 nodes per wave, 4 waves per block

    // ----- layer 1: x -> root1 + table0; fused {agg+relu} x {gemm w1} -> table1 -----
    gemm2_mfma<128><<<ggrid, 256, 0, stream>>>(x, v1t, w1it, rootb, tblA, dinv, N, HID, 128, 0);
    agg_gemm_kernel<HID, HID, 0><<<ntiles, 512, 0, stream>>>(
        tblA, row_ptr, col, dinv, rootb, b1, w1t, nullptr, nullptr, tblB, N);

    // ----- layer 2 entry: fused {agg+relu+mean} x {gemm v2 & w2_init} -> root2 + table2 -----
    agg_gemm_kernel<HID, NCLS, 1><<<ntiles, 512, 0, stream>>>(
        tblB, row_ptr, col, dinv, rootb, b1, v2t, w2it, root2, tblA, N);

    // ----- layer 2, t=1: fused {agg (no relu)} x {gemm w2} -> table3 -----
    agg_gemm_kernel<NCLS, NCLS, 2><<<ntiles, 512, 0, stream>>>(
        tblA, row_ptr, col, dinv, root2, b2, w2t, nullptr, nullptr, tblB, N);

    // ----- final aggregation: mean over k + log_softmax -----
    agg_kernel<NCLS><<<agg_blocks, 256, 0, stream>>>(tblB, row_ptr, col, dinv, root2, b2,
                                                     (float*)d_out, N, 0, 2);
}

// Round 3
// 273.541 us; speedup vs baseline: 1.1052x; 1.0031x over previous
//
#include <hip/hip_runtime.h>
#include <hip/hip_bf16.h>
#include <math.h>

#define N_NODES 50000
#define F_IN 128
#define HID 64
#define NCLS 40
#define K_STACKS 2
#define SCAN_TILE 1024
#define NBLK_CNT 256  // radix blocks; 256 buckets of 256 node-ids (N=50000 -> 196 used)

typedef __attribute__((ext_vector_type(8))) short short8;
typedef __attribute__((ext_vector_type(4))) float floatx4;
typedef __attribute__((ext_vector_type(2))) float floatx2;

__device__ __forceinline__ unsigned int f32_to_bf16_bits(float f) {
    unsigned int u = __float_as_uint(f);
    return (u + 0x7fffu + ((u >> 16) & 1u)) >> 16;  // RNE
}
__device__ __forceinline__ unsigned int pack_bf16x2(float a, float b) {
    return f32_to_bf16_bits(a) | (f32_to_bf16_bits(b) << 16);
}
__device__ __forceinline__ unsigned char f32_to_fp8(float v) {
    int pk = __builtin_amdgcn_cvt_pk_fp8_f32(v, v, 0, false);  // OCP e4m3 on gfx950
    return (unsigned char)(pk & 0xff);
}

// ---------------- CSR build via radix bucketing (dst>>8) ----------------
// NOTE: packing src into 16 bits requires N <= 65536 (here N=50000).

__global__ __launch_bounds__(256) void count_kernel(const int* __restrict__ dst,
                                                    int* __restrict__ counts,
                                                    int* __restrict__ tileSums, int E) {
    __shared__ int hist[256];
    __shared__ int ts[64];
    int blk = blockIdx.x, t = threadIdx.x;
    hist[t] = 0;
    if (t < 64) ts[t] = 0;
    __syncthreads();
    int chunk = (E + NBLK_CNT - 1) / NBLK_CNT;
    int s = blk * chunk, e = min(E, s + chunk);
    for (int i = s + t; i < e; i += 256) atomicAdd(&hist[dst[i] >> 8], 1);
    __syncthreads();
    counts[t * NBLK_CNT + blk] = hist[t];  // bucket-major
    atomicAdd(&ts[t >> 2], hist[t]);
    __syncthreads();
    if (t < 64) atomicAdd(&tileSums[t], ts[t]);
}

__global__ __launch_bounds__(256) void scan_phase3_excl(const int* __restrict__ in,
                                                        const int* __restrict__ tileSums,
                                                        int* __restrict__ out, int n) {
    __shared__ int lds[256];
    __shared__ int tsum[64];
    int b = blockIdx.x, t = threadIdx.x;
    if (t < 64) tsum[t] = tileSums[t];
    int base = b * SCAN_TILE + t * 4;
    int e[4];
    int s = 0;
#pragma unroll
    for (int i = 0; i < 4; ++i) {
        e[i] = (base + i < n) ? in[base + i] : 0;
        s += e[i];
    }
    lds[t] = s;
    __syncthreads();
    int v = s;
    for (int off = 1; off < 256; off <<= 1) {
        int add = (t >= off) ? lds[t - off] : 0;
        __syncthreads();
        v += add;
        lds[t] = v;
        __syncthreads();
    }
    int toff = 0;
    for (int i = 0; i < b; ++i) toff += tsum[i];
    int run = (t == 0 ? 0 : lds[t - 1]) + toff;
#pragma unroll
    for (int i = 0; i < 4; ++i) {
        if (base + i < n) {
            out[base + i] = run;
            run += e[i];
        }
    }
}

__global__ __launch_bounds__(256) void bucket_scatter_kernel(const int* __restrict__ src,
                                                             const int* __restrict__ dst,
                                                             const int* __restrict__ scanned,
                                                             unsigned int* __restrict__ pairs,
                                                             int E) {
    __shared__ int cur[256];
    int blk = blockIdx.x, t = threadIdx.x;
    cur[t] = scanned[t * NBLK_CNT + blk];
    __syncthreads();
    int chunk = (E + NBLK_CNT - 1) / NBLK_CNT;
    int s0 = blk * chunk, e0 = min(E, s0 + chunk);
    for (int i = s0 + t; i < e0; i += 256) {
        int d = dst[i];
        int pos = atomicAdd(&cur[d >> 8], 1);
        pairs[pos] = (unsigned int)src[i] | ((unsigned int)(d & 255) << 16);
    }
}

__global__ __launch_bounds__(256) void csr_build_kernel(const unsigned int* __restrict__ pairs,
                                                        const int* __restrict__ scanned,
                                                        int* __restrict__ row_ptr,
                                                        float* __restrict__ dinv,
                                                        int* __restrict__ col, int N, int E) {
    __shared__ int degl[256], lds[256], curl[256], sb[2];
    int b = blockIdx.x, t = threadIdx.x;
    if (t == 0) {
        sb[0] = scanned[b * NBLK_CNT];
        sb[1] = (b + 1 < 256) ? scanned[(b + 1) * NBLK_CNT] : E;
    }
    degl[t] = 0;
    __syncthreads();
    int bstart = sb[0], bend = sb[1];
    for (int e = bstart + t; e < bend; e += 256) {
        atomicAdd(&degl[(pairs[e] >> 16) & 255], 1);
    }
    __syncthreads();
    int d = degl[t];
    lds[t] = d;
    __syncthreads();
    int v = d;
    for (int off = 1; off < 256; off <<= 1) {
        int add = (t >= off) ? lds[t - off] : 0;
        __syncthreads();
        v += add;
        lds[t] = v;
        __syncthreads();
    }
    int excl = v - d;
    int node = b * 256 + t;
    if (node <= N) row_ptr[node] = bstart + excl;
    if (node < N) dinv[node] = (d > 0) ? (1.0f / sqrtf((float)d)) : 0.0f;
    curl[t] = excl;
    __syncthreads();
    for (int e = bstart + t; e < bend; e += 256) {
        unsigned int p = pairs[e];
        int ln = (p >> 16) & 255;
        int pos = atomicAdd(&curl[ln], 1);
        col[bstart + pos] = (int)(p & 0xffffu);
    }
}

// ---------------- fused weight pre-transpose: [k][C][F] fp32 -> [k][F][CP] bf16 ----------
__device__ __forceinline__ void wt_one(const float* __restrict__ in,
                                       unsigned short* __restrict__ out, int li, int C, int F,
                                       int CP) {
    int k = li / (F * CP);
    int r = li - k * F * CP;
    int f = r / CP;
    int c = r - f * CP;
    out[li] = (c < C) ? (unsigned short)f32_to_bf16_bits(in[((size_t)k * C + c) * F + f]) : 0;
}

__global__ void wt_all_kernel(const float* v1, const float* w1i, const float* w1,
                              const float* v2, const float* w2i, const float* w2,
                              unsigned short* v1t, unsigned short* w1it, unsigned short* w1t,
                              unsigned short* v2t, unsigned short* w2it, unsigned short* w2t) {
    int i = blockIdx.x * blockDim.x + threadIdx.x;
    if (i < 16384) wt_one(v1, v1t, i, 128, 64, 128);
    else if (i < 32768) wt_one(w1i, w1it, i - 16384, 128, 64, 128);
    else if (i < 40960) wt_one(w1, w1t, i - 32768, 64, 64, 64);
    else if (i < 46080) wt_one(v2, v2t, i - 40960, 64, 40, 64);
    else if (i < 51200) wt_one(w2i, w2it, i - 46080, 64, 40, 64);
    else if (i < 56320) wt_one(w2, w2t, i - 51200, 40, 40, 64);
}

// ---------------- staging helpers ----------------
template <int CINP>
__device__ __forceinline__ void stage_A(const void* A, unsigned short* At, size_t abase,
                                        int n0, int t, int N, int CREAL, int a_bf16,
                                        int stride) {
    constexpr int CP8 = CINP / 8;
    constexpr int MS = CP8 - 1;
    constexpr int SH = (CP8 == 16) ? 4 : 3;
    for (int i = t; i < 64 * CP8; i += stride) {
        int n = i >> SH;
        int c = i & MS;
        uint4 w = make_uint4(0u, 0u, 0u, 0u);
        int gn = n0 + n;
        if (gn < N && c * 8 < CREAL) {
            if (a_bf16) {
                w = *(const uint4*)((const unsigned short*)A + abase + (size_t)gn * CREAL + c * 8);
            } else {
                const float* srcp = (const float*)A + abase + (size_t)gn * CREAL + c * 8;
                float4 f0 = *(const float4*)(srcp);
                float4 f1 = *(const float4*)(srcp + 4);
                w.x = pack_bf16x2(f0.x, f0.y);
                w.y = pack_bf16x2(f0.z, f0.w);
                w.z = pack_bf16x2(f1.x, f1.y);
                w.w = pack_bf16x2(f1.z, f1.w);
            }
        }
        *(uint4*)(At + n * CINP + ((c ^ (n & MS)) << 3)) = w;
    }
}

template <int CINP>
__device__ __forceinline__ void stage_B(const unsigned short* Bk, unsigned short* Bs, int t,
                                        int COUT, int stride) {
    constexpr int CP8 = CINP / 8;
    constexpr int MS = CP8 - 1;
    constexpr int SH = (CP8 == 16) ? 4 : 3;
    for (int i = t; i < COUT * CP8; i += stride) {
        int f = i >> SH;
        int c = i & MS;
        uint4 w = *(const uint4*)(Bk + f * CINP + c * 8);
        *(uint4*)(Bs + f * CINP + ((c ^ (f & MS)) << 3)) = w;
    }
}

// ---------------- layer-1 entry GEMM v3: 512 threads, k split across wave halves ----------
// A tile (64 rows of x, f32->bf16) staged once in LDS; B fragments read DIRECTLY from
// global Bt (linear pre-transposed layout == MFMA fragment layout; 64KB total, L2-hot).
// out1 = root (bf16 std [k][N][64]); out2 = fp8 gather table [node][k][64], dinv-scaled.
__global__ __launch_bounds__(512) void gemm2k(
    const float* __restrict__ A, const unsigned short* __restrict__ Bt1,
    const unsigned short* __restrict__ Bt2, unsigned short* __restrict__ out1,
    unsigned char* __restrict__ out2, const float* __restrict__ scale, int N) {
    constexpr int CINP = 128;
    constexpr int MS = 15;
    __shared__ __align__(16) unsigned short At[64 * CINP];

    const int n0 = blockIdx.x * 64;
    const int t = threadIdx.x;
    stage_A<CINP>(A, At, (size_t)0, n0, t, N, CINP, 0, 512);
    __syncthreads();

    const int lane = t & 63;
    const int wv = t >> 6;       // 0..7
    const int kSel = wv >> 2;    // waves 0-3 -> k=0, waves 4-7 -> k=1
    const int m0 = (wv & 3) * 16;
    const int quad = lane >> 4;
    const int li = lane & 15;
    const int am = (m0 + li) & MS;
    const unsigned short* B1k = Bt1 + (size_t)kSel * 64 * CINP;
    const unsigned short* B2k = Bt2 + (size_t)kSel * 64 * CINP;

    floatx4 acc1[4] = {{0.f, 0.f, 0.f, 0.f}, {0.f, 0.f, 0.f, 0.f},
                       {0.f, 0.f, 0.f, 0.f}, {0.f, 0.f, 0.f, 0.f}};
    floatx4 acc2[4] = {{0.f, 0.f, 0.f, 0.f}, {0.f, 0.f, 0.f, 0.f},
                       {0.f, 0.f, 0.f, 0.f}, {0.f, 0.f, 0.f, 0.f}};
#pragma unroll
    for (int kc = 0; kc < 4; ++kc) {
        int cc = kc * 4 + quad;
        short8 a = *(const short8*)(At + (m0 + li) * CINP + ((cc ^ am) << 3));
#pragma unroll
        for (int nt = 0; nt < 4; ++nt) {
            int f = nt * 16 + li;
            size_t bo = (size_t)f * CINP + cc * 8;
            short8 b1 = *(const short8*)(B1k + bo);
            short8 b2 = *(const short8*)(B2k + bo);
            acc1[nt] = __builtin_amdgcn_mfma_f32_16x16x32_bf16(a, b1, acc1[nt], 0, 0, 0);
            acc2[nt] = __builtin_amdgcn_mfma_f32_16x16x32_bf16(a, b2, acc2[nt], 0, 0, 0);
        }
    }

    float sc[4];
#pragma unroll
    for (int r = 0; r < 4; ++r) {
        int node = n0 + m0 + quad * 4 + r;
        sc[r] = (node < N) ? scale[node] : 1.f;
    }
#pragma unroll
    for (int nt = 0; nt < 4; ++nt) {
        int f = nt * 16 + li;
#pragma unroll
        for (int r = 0; r < 4; ++r) {
            int node = n0 + m0 + quad * 4 + r;
            if (node < N) {
                out1[((size_t)kSel * N + node) * 64 + f] =
                    (unsigned short)f32_to_bf16_bits(acc1[nt][r]);
                out2[(size_t)node * 128 + (size_t)kSel * 64 + f] =
                    f32_to_fp8(acc2[nt][r] * sc[r]);
            }
        }
    }
}

// ---------------- fused aggregation + GEMM (512 threads / 8 waves) ----------------
// Phase 1: per-wave gather/aggregate (2 nodes per pass, 4 passes -> 8 rows/wave); epilogue
// (dinv scale + root + bias [+relu][+mean-over-k]) writes straight into swizzled LDS A-tile.
// Phase 2: MFMA over the LDS tile; waves 0-3 compute k=0, waves 4-7 compute k=1.
// FMODE 0: per-k A, relu       (layer 1, t=1)    COUT=64, 1 B/k
// FMODE 1: mean-over-k A, relu (layer 2 entry)   COUT=40, 2 B/k  (root out + table out)
// FMODE 2: per-k A, no relu    (layer 2, t=1)    COUT=40, 1 B/k
template <int F, int COUT, int FMODE>
__global__ __launch_bounds__(512) void agg_gemm_kernel(
    const unsigned char* __restrict__ h8, const int* __restrict__ row_ptr,
    const int* __restrict__ col, const float* __restrict__ dinv,
    const unsigned short* __restrict__ rootb, const float* __restrict__ bias,
    const unsigned short* __restrict__ Bt1, const unsigned short* __restrict__ Bt2,
    unsigned short* __restrict__ rootOut, unsigned char* __restrict__ tblOut, int N) {
    constexpr int NA = (FMODE == 1) ? 1 : 2;
    constexpr int NB = (FMODE == 1) ? 4 : 2;
    constexpr int BT = COUT * 64;
    constexpr int NT = (COUT + 15) / 16;
    constexpr int FH = F / 8;
    constexpr int ROWB = 2 * F;
    __shared__ __align__(16) unsigned short At[NA * 64 * 64];
    __shared__ __align__(16) unsigned short Bs[NB * BT];
    __shared__ int rp[65];
    __shared__ float dvl[64];

    const int n0 = blockIdx.x * 64;
    const int t = threadIdx.x;

    stage_B<64>(Bt1, Bs, t, COUT, 512);
    stage_B<64>(Bt1 + (size_t)COUT * 64, Bs + BT, t, COUT, 512);
    if constexpr (FMODE == 1) {
        stage_B<64>(Bt2, Bs + 2 * BT, t, COUT, 512);
        stage_B<64>(Bt2 + (size_t)COUT * 64, Bs + 3 * BT, t, COUT, 512);
    }
    if (t < 65) rp[t] = row_ptr[min(n0 + t, N)];
    if (t < 64) dvl[t] = (n0 + t < N) ? dinv[n0 + t] : 0.f;
    __syncthreads();

    const int lane = t & 63;
    const int wv = t >> 6;  // 0..7
    const int half = lane >> 5;
    const int l32 = lane & 31;
    const int sub = l32 >> 4;
    const int fq = l32 & 15;
    const int kk = fq >> 3;
    const int fqq = fq & 7;
    const int fqc = (fqq < FH) ? fqq : (FH - 1);
    const int foff = kk * F + fqc * 8;

    // ---- phase 1: each wave aggregates 8 rows (4 passes x 2 nodes) into LDS A ----
#pragma unroll 1
    for (int p = 0; p < 4; ++p) {
        const int nl = wv * 8 + p * 2 + half;
        const int node = n0 + nl;
        const bool valid = node < N;
        const int e0 = rp[nl];
        const int deg = rp[nl + 1] - e0;
        const float dv = dvl[nl];
        float acc[8] = {};
        for (int w0 = 0; w0 < deg; w0 += 32) {
            int mye = w0 + l32;
            int c = (mye < deg) ? col[e0 + mye] : 0;
            int nch = min(deg - w0, 32);
            for (int base = 0; base < nch; base += 16) {
                uint2 v[8];
                float wj[8];
#pragma unroll
                for (int u = 0; u < 8; ++u) {
                    int j = base + u * 2 + sub;
                    int cj = __shfl(c, (half << 5) | (j & 31));
                    bool ok = (j < nch);
                    wj[u] = ok ? 1.f : 0.f;
                    int cs = ok ? cj : 0;
                    v[u] = *(const uint2*)(h8 + (size_t)cs * ROWB + foff);
                }
#pragma unroll
                for (int u = 0; u < 8; ++u) {
                    floatx2 f0 = __builtin_amdgcn_cvt_pk_f32_fp8(v[u].x, false);
                    floatx2 f1 = __builtin_amdgcn_cvt_pk_f32_fp8(v[u].x, true);
                    floatx2 f2 = __builtin_amdgcn_cvt_pk_f32_fp8(v[u].y, false);
                    floatx2 f3 = __builtin_amdgcn_cvt_pk_f32_fp8(v[u].y, true);
                    acc[0] += wj[u] * f0.x;
                    acc[1] += wj[u] * f0.y;
                    acc[2] += wj[u] * f1.x;
                    acc[3] += wj[u] * f1.y;
                    acc[4] += wj[u] * f2.x;
                    acc[5] += wj[u] * f2.y;
                    acc[6] += wj[u] * f3.x;
                    acc[7] += wj[u] * f3.y;
                }
            }
        }
#pragma unroll
        for (int i = 0; i < 8; ++i) acc[i] += __shfl_xor(acc[i], 16);

        size_t oc = ((size_t)kk * N + (valid ? node : 0)) * F + fqc * 8;
        uint4 rv = *(const uint4*)(rootb + oc);
        const float* bp = bias + kk * F + fqc * 8;
        float4 b0 = *(const float4*)(bp);
        float4 b1_ = *(const float4*)(bp + 4);
        const unsigned int ru[4] = {rv.x, rv.y, rv.z, rv.w};
        float res[8];
#pragma unroll
        for (int q = 0; q < 4; ++q) {
            float rlo = __uint_as_float(ru[q] << 16);
            float rhi = __uint_as_float(ru[q] & 0xffff0000u);
            float blo = (q < 2) ? ((q == 0) ? b0.x : b0.z) : ((q == 2) ? b1_.x : b1_.z);
            float bhi = (q < 2) ? ((q == 0) ? b0.y : b0.w) : ((q == 2) ? b1_.y : b1_.w);
            res[2 * q] = acc[2 * q] * dv + rlo + blo;
            res[2 * q + 1] = acc[2 * q + 1] * dv + rhi + bhi;
        }
        if constexpr (FMODE != 2) {
#pragma unroll
            for (int i = 0; i < 8; ++i) res[i] = fmaxf(res[i], 0.f);
        }
        if constexpr (FMODE == 1) {
            float mres[8];
#pragma unroll
            for (int i = 0; i < 8; ++i) mres[i] = 0.5f * (res[i] + __shfl_xor(res[i], 8));
            if (sub == 0 && kk == 0) {
                uint4 w;
                w.x = pack_bf16x2(mres[0], mres[1]);
                w.y = pack_bf16x2(mres[2], mres[3]);
                w.z = pack_bf16x2(mres[4], mres[5]);
                w.w = pack_bf16x2(mres[6], mres[7]);
                *(uint4*)(At + nl * 64 + ((fqq ^ (nl & 7)) << 3)) = w;
            }
        } else {
            if (sub == 0) {
                uint4 w = make_uint4(0u, 0u, 0u, 0u);
                if (fqq < FH) {
                    w.x = pack_bf16x2(res[0], res[1]);
                    w.y = pack_bf16x2(res[2], res[3]);
                    w.z = pack_bf16x2(res[4], res[5]);
                    w.w = pack_bf16x2(res[6], res[7]);
                }
                *(uint4*)(At + kk * 4096 + nl * 64 + ((fqq ^ (nl & 7)) << 3)) = w;
            }
        }
    }
    __syncthreads();

    // ---- phase 2: MFMA over LDS tile(s); waves 0-3 -> k=0, waves 4-7 -> k=1 ----
    const int quad = lane >> 4;
    const int li = lane & 15;
    const int kSel = wv >> 2;
    const int m0 = (wv & 3) * 16;
    const int am = (m0 + li) & 7;

    if constexpr (FMODE == 1) {
        floatx4 aR[NT] = {};
        floatx4 aT[NT] = {};
#pragma unroll
        for (int kc = 0; kc < 2; ++kc) {
            int cc = kc * 4 + quad;
            short8 a = *(const short8*)(At + (m0 + li) * 64 + ((cc ^ am) << 3));
#pragma unroll
            for (int nt = 0; nt < NT; ++nt) {
                int f = nt * 16 + li;
                int fc = (COUT & 15) ? ((f < COUT) ? f : (COUT - 1)) : f;
                int bo = fc * 64 + ((cc ^ (fc & 7)) << 3);
                short8 bR = *(const short8*)(Bs + kSel * BT + bo);
                short8 bT = *(const short8*)(Bs + (2 + kSel) * BT + bo);
                aR[nt] = __builtin_amdgcn_mfma_f32_16x16x32_bf16(a, bR, aR[nt], 0, 0, 0);
                aT[nt] = __builtin_amdgcn_mfma_f32_16x16x32_bf16(a, bT, aT[nt], 0, 0, 0);
            }
        }
#pragma unroll
        for (int nt = 0; nt < NT; ++nt) {
            int f = nt * 16 + li;
            if (f >= COUT) continue;
#pragma unroll
            for (int r = 0; r < 4; ++r) {
                int nl2 = m0 + quad * 4 + r;
                int node = n0 + nl2;
                if (node < N) {
                    rootOut[((size_t)kSel * N + node) * COUT + f] =
                        (unsigned short)f32_to_bf16_bits(aR[nt][r]);
                    tblOut[(size_t)node * 2 * COUT + (size_t)kSel * COUT + f] =
                        f32_to_fp8(aT[nt][r] * dvl[nl2]);
                }
            }
        }
    } else {
        floatx4 ac[NT] = {};
#pragma unroll
        for (int kc = 0; kc < 2; ++kc) {
            int cc = kc * 4 + quad;
            short8 a = *(const short8*)(At + kSel * 4096 + (m0 + li) * 64 + ((cc ^ am) << 3));
#pragma unroll
            for (int nt = 0; nt < NT; ++nt) {
                int f = nt * 16 + li;
                int fc = (COUT & 15) ? ((f < COUT) ? f : (COUT - 1)) : f;
                int bo = fc * 64 + ((cc ^ (fc & 7)) << 3);
                short8 b = *(const short8*)(Bs + kSel * BT + bo);
                ac[nt] = __builtin_amdgcn_mfma_f32_16x16x32_bf16(a, b, ac[nt], 0, 0, 0);
            }
        }
#pragma unroll
        for (int nt = 0; nt < NT; ++nt) {
            int f = nt * 16 + li;
            if (f >= COUT) continue;
#pragma unroll
            for (int r = 0; r < 4; ++r) {
                int nl2 = m0 + quad * 4 + r;
                int node = n0 + nl2;
                if (node < N)
                    tblOut[(size_t)node * 2 * COUT + (size_t)kSel * COUT + f] =
                        f32_to_fp8(ac[nt][r] * dvl[nl2]);
            }
        }
    }
}

// ---------------- final sparse aggregation: fp8 table, 2 nodes/wave, fused mean+lsm --------
template <int F>
__global__ __launch_bounds__(256) void agg_kernel(
    const unsigned char* __restrict__ h8, const int* __restrict__ row_ptr,
    const int* __restrict__ col, const float* __restrict__ dinv,
    const unsigned short* __restrict__ rootb, const float* __restrict__ bias,
    void* __restrict__ out, int N, int do_relu, int mode) {
    constexpr int FH = F / 8;
    constexpr int ROWB = 2 * F;  // interleaved row bytes (fp8)
    int wid = (blockIdx.x * blockDim.x + threadIdx.x) >> 6;
    int lane = threadIdx.x & 63;
    int half = lane >> 5;
    int l32 = lane & 31;
    int node = wid * 2 + half;
    bool valid = node < N;
    int e0 = 0, deg = 0;
    float dv = 0.f;
    if (valid) {
        e0 = row_ptr[node];
        deg = row_ptr[node + 1] - e0;
        dv = dinv[node];
    }
    const int sub = l32 >> 4;
    const int fq = l32 & 15;
    const int kk = fq >> 3;
    const int fqq = fq & 7;
    const int fqc = (fqq < FH) ? fqq : (FH - 1);
    const int foff = kk * F + fqc * 8;

    float acc[8] = {};
    for (int w0 = 0; w0 < deg; w0 += 32) {
        int mye = w0 + l32;
        int c = (mye < deg) ? col[e0 + mye] : 0;
        int nch = min(deg - w0, 32);
        for (int base = 0; base < nch; base += 16) {
            uint2 v[8];
            float wj[8];
#pragma unroll
            for (int u = 0; u < 8; ++u) {
                int j = base + u * 2 + sub;
                int cj = __shfl(c, (half << 5) | (j & 31));
                bool ok = (j < nch);
                wj[u] = ok ? 1.f : 0.f;
                int cs = ok ? cj : 0;
                v[u] = *(const uint2*)(h8 + (size_t)cs * ROWB + foff);
            }
#pragma unroll
            for (int u = 0; u < 8; ++u) {
                floatx2 f0 = __builtin_amdgcn_cvt_pk_f32_fp8(v[u].x, false);
                floatx2 f1 = __builtin_amdgcn_cvt_pk_f32_fp8(v[u].x, true);
                floatx2 f2 = __builtin_amdgcn_cvt_pk_f32_fp8(v[u].y, false);
                floatx2 f3 = __builtin_amdgcn_cvt_pk_f32_fp8(v[u].y, true);
                acc[0] += wj[u] * f0.x;
                acc[1] += wj[u] * f0.y;
                acc[2] += wj[u] * f1.x;
                acc[3] += wj[u] * f1.y;
                acc[4] += wj[u] * f2.x;
                acc[5] += wj[u] * f2.y;
                acc[6] += wj[u] * f3.x;
                acc[7] += wj[u] * f3.y;
            }
        }
    }
#pragma unroll
    for (int i = 0; i < 8; ++i) acc[i] += __shfl_xor(acc[i], 16);

    size_t oc = ((size_t)kk * N + (valid ? node : 0)) * F + fqc * 8;
    uint4 rv = *(const uint4*)(rootb + oc);
    const float* bp = bias + kk * F + fqc * 8;
    float4 b0 = *(const float4*)(bp);
    float4 b1 = *(const float4*)(bp + 4);
    const unsigned int ru[4] = {rv.x, rv.y, rv.z, rv.w};
    float res[8];
#pragma unroll
    for (int q = 0; q < 4; ++q) {
        float rlo = __uint_as_float(ru[q] << 16);
        float rhi = __uint_as_float(ru[q] & 0xffff0000u);
        float blo = (q < 2) ? ((q == 0) ? b0.x : b0.z) : ((q == 2) ? b1.x : b1.z);
        float bhi = (q < 2) ? ((q == 0) ? b0.y : b0.w) : ((q == 2) ? b1.y : b1.w);
        res[2 * q] = acc[2 * q] * dv + rlo + blo;
        res[2 * q + 1] = acc[2 * q + 1] * dv + rhi + bhi;
    }
    if (do_relu) {
#pragma unroll
        for (int i = 0; i < 8; ++i) res[i] = fmaxf(res[i], 0.f);
    }
    if (mode == 0) {
        if (sub == 0 && fqq < FH && valid) {
            size_t o = ((size_t)kk * N + node) * F + fqq * 8;
            uint4 w;
            w.x = pack_bf16x2(res[0], res[1]);
            w.y = pack_bf16x2(res[2], res[3]);
            w.z = pack_bf16x2(res[4], res[5]);
            w.w = pack_bf16x2(res[6], res[7]);
            *(uint4*)((unsigned short*)out + o) = w;
        }
    } else {
        float mres[8];
#pragma unroll
        for (int i = 0; i < 8; ++i) mres[i] = 0.5f * (res[i] + __shfl_xor(res[i], 8));
        if (mode == 1) {
            if (sub == 0 && kk == 0 && fqq < FH && valid) {
                size_t o = (size_t)node * F + fqq * 8;
                *(float4*)((float*)out + o) = make_float4(mres[0], mres[1], mres[2], mres[3]);
                *(float4*)((float*)out + o + 4) = make_float4(mres[4], mres[5], mres[6], mres[7]);
            }
        } else {
            bool act = (fqq < FH);
            float lm = -INFINITY;
            if (act) {
#pragma unroll
                for (int i = 0; i < 8; ++i) lm = fmaxf(lm, mres[i]);
            }
#pragma unroll
            for (int m = 1; m < 8; m <<= 1) lm = fmaxf(lm, __shfl_xor(lm, m));
            float ls = 0.f;
            if (act) {
#pragma unroll
                for (int i = 0; i < 8; ++i) ls += expf(mres[i] - lm);
            }
#pragma unroll
            for (int m = 1; m < 8; m <<= 1) ls += __shfl_xor(ls, m);
            float lg = lm + logf(ls);
            if (sub == 0 && kk == 0 && act && valid) {
                size_t o = (size_t)node * F + fqq * 8;
                *(float4*)((float*)out + o) =
                    make_float4(mres[0] - lg, mres[1] - lg, mres[2] - lg, mres[3] - lg);
                *(float4*)((float*)out + o + 4) =
                    make_float4(mres[4] - lg, mres[5] - lg, mres[6] - lg, mres[7] - lg);
            }
        }
    }
}

// ---------------- launch ----------------

static inline size_t align256(size_t x) { return (x + 255) & ~(size_t)255; }

extern "C" void kernel_launch(void* const* d_in, const int* in_sizes, int n_in,
                              void* d_out, int out_size, void* d_ws, size_t ws_size,
                              hipStream_t stream) {
    const float* x = (const float*)d_in[0];
    const int* ei = (const int*)d_in[1];
    const float* w1_init = (const float*)d_in[2];
    const float* w1 = (const float*)d_in[3];
    const float* v1 = (const float*)d_in[4];
    const float* b1 = (const float*)d_in[5];
    const float* w2_init = (const float*)d_in[6];
    const float* w2 = (const float*)d_in[7];
    const float* v2 = (const float*)d_in[8];
    const float* b2 = (const float*)d_in[9];

    const int N = in_sizes[0] / F_IN;
    const int E = in_sizes[1] / 2;
    const int* src = ei;
    const int* dst = ei + E;

    char* p = (char*)d_ws;
    auto take = [&](size_t bytes) {
        char* r = p;
        p += align256(bytes);
        return r;
    };
    float* dinv = (float*)take((size_t)N * 4);
    int* row_ptr = (int*)take((size_t)(N + 1) * 4);
    int* tileSums = (int*)take(256 * 4);
    int* counts = (int*)take((size_t)256 * NBLK_CNT * 4);
    int* scanned = (int*)take((size_t)256 * NBLK_CNT * 4);
    unsigned int* pairs = (unsigned int*)take((size_t)E * 4);
    int* col = (int*)take((size_t)E * 4);
    unsigned short* v1t = (unsigned short*)take((size_t)2 * 64 * 128 * 2);
    unsigned short* w1it = (unsigned short*)take((size_t)2 * 64 * 128 * 2);
    unsigned short* w1t = (unsigned short*)take((size_t)2 * 64 * 64 * 2);
    unsigned short* v2t = (unsigned short*)take((size_t)2 * 40 * 64 * 2);
    unsigned short* w2it = (unsigned short*)take((size_t)2 * 40 * 64 * 2);
    unsigned short* w2t = (unsigned short*)take((size_t)2 * 40 * 64 * 2);
    unsigned short* rootb = (unsigned short*)take((size_t)K_STACKS * N * HID * 2);
    unsigned short* root2 = (unsigned short*)take((size_t)K_STACKS * N * NCLS * 2);
    unsigned char* tblA = (unsigned char*)take((size_t)K_STACKS * N * HID);
    unsigned char* tblB = (unsigned char*)take((size_t)K_STACKS * N * HID);

    const int TB = 256;
    const int nCnt = 256 * NBLK_CNT;           // 65536
    const int nScanBlocks = nCnt / SCAN_TILE;  // 64
    const int nBuckets = (N + 255) / 256;      // 196
    const int ntiles = (N + 63) / 64;          // 782

    hipMemsetAsync(tileSums, 0, 256, stream);
    count_kernel<<<NBLK_CNT, 256, 0, stream>>>(dst, counts, tileSums, E);
    scan_phase3_excl<<<nScanBlocks, 256, 0, stream>>>(counts, tileSums, scanned, nCnt);
    bucket_scatter_kernel<<<NBLK_CNT, 256, 0, stream>>>(src, dst, scanned, pairs, E);
    csr_build_kernel<<<nBuckets, 256, 0, stream>>>(pairs, scanned, row_ptr, dinv, col, N, E);

    wt_all_kernel<<<(56320 + TB - 1) / TB, TB, 0, stream>>>(v1, w1_init, w1, v2, w2_init, w2,
                                                            v1t, w1it, w1t, v2t, w2it, w2t);

    const int agg_blocks = ((N + 1) / 2 + 3) / 4;  // 2 nodes per wave, 4 waves per block

    // ----- layer 1: x -> root1 + table0; fused {agg+relu} x {gemm w1} -> table1 -----
    gemm2k<<<ntiles, 512, 0, stream>>>(x, v1t, w1it, rootb, tblA, dinv, N);
    agg_gemm_kernel<HID, HID, 0><<<ntiles, 512, 0, stream>>>(
        tblA, row_ptr, col, dinv, rootb, b1, w1t, nullptr, nullptr, tblB, N);

    // ----- layer 2 entry: fused {agg+relu+mean} x {gemm v2 & w2_init} -> root2 + table2 -----
    agg_gemm_kernel<HID, NCLS, 1><<<ntiles, 512, 0, stream>>>(
        tblB, row_ptr, col, dinv, rootb, b1, v2t, w2it, root2, tblA, N);

    // ----- layer 2, t=1: fused {agg (no relu)} x {gemm w2} -> table3 -----
    agg_gemm_kernel<NCLS, NCLS, 2><<<ntiles, 512, 0, stream>>>(
        tblA, row_ptr, col, dinv, root2, b2, w2t, nullptr, nullptr, tblB, N);

    // ----- final aggregation: mean over k + log_softmax -----
    agg_kernel<NCLS><<<agg_blocks, 256, 0, stream>>>(tblB, row_ptr, col, dinv, root2, b2,
                                                     (float*)d_out, N, 0, 2);
}